// Round 5
// baseline (798.017 us; speedup 1.0000x reference)
//
#include <hip/hip_runtime.h>
#include <cstdint>
#include <cstddef>

typedef __bf16 bf16;
typedef __bf16 bf16x8 __attribute__((ext_vector_type(8)));
typedef __bf16 bf16x4 __attribute__((ext_vector_type(4)));
typedef float f32x4 __attribute__((ext_vector_type(4)));

#define D_MODEL 2048
#define NH 16
#define HD 128
#define LQ 2048
#define LT 4096

__device__ __forceinline__ void gload16(const void* g, void* l) {
  __builtin_amdgcn_global_load_lds((const __attribute__((address_space(1))) void*)g,
                                   (__attribute__((address_space(3))) void*)l, 16, 0, 0);
}

// ---------------- elementwise fp32 -> bf16 ----------------
__global__ __launch_bounds__(256) void conv_bf16(const float* __restrict__ s, bf16* __restrict__ d, int n) {
  int i = (blockIdx.x * 256 + threadIdx.x) * 4;
  if (i >= n) return;
  float4 v = *(const float4*)(s + i);
  bf16x4 o = { (bf16)v.x, (bf16)v.y, (bf16)v.z, (bf16)v.w };
  *(bf16x4*)(d + i) = o;
}

// ---------------- copy past K/V into cache (fp32 out, optional bf16) ----------------
// src layout [BH][2048][128]; dst layout [BH][4096][128] rows 0..2047
__global__ __launch_bounds__(256) void copy_past(const float* __restrict__ src, float* __restrict__ dstf,
                                                 bf16* __restrict__ dstb) {
  int i = (blockIdx.x * 256 + threadIdx.x) * 4;
  int bh = i >> 18;          // / (2048*128)
  int rem = i & 262143;
  size_t o = ((size_t)bh << 19) + rem;   // * (4096*128)
  float4 v = *(const float4*)(src + i);
  *(float4*)(dstf + o) = v;
  if (dstb) {
    bf16x4 ob = { (bf16)v.x, (bf16)v.y, (bf16)v.z, (bf16)v.w };
    *(bf16x4*)(dstb + o) = ob;
  }
}

// ---------------- shared 128x128 bf16 GEMM mainloop (C = A * B^T), K = 2048 ----------------
__device__ __forceinline__ void gemm128_mainloop(const bf16* __restrict__ A, const bf16* __restrict__ B,
                                                 int m0, int n0, bf16* As, bf16* Bs, f32x4 (&acc)[4][4]) {
  const int tid = threadIdx.x, lane = tid & 63, w = tid >> 6;
  const int srow = w * 8 + (lane >> 3), scol = (lane & 7) * 8;
  const int wm = (w >> 1) * 64, wn = (w & 1) * 64, fr = lane & 15, fg = lane >> 4;
  for (int k0 = 0; k0 < 2048; k0 += 64) {
#pragma unroll
    for (int i = 0; i < 4; i++) {
      gload16(A + (size_t)(m0 + i * 32 + srow) * 2048 + k0 + scol, As + (i * 32 + w * 8) * 64);
      gload16(B + (size_t)(n0 + i * 32 + srow) * 2048 + k0 + scol, Bs + (i * 32 + w * 8) * 64);
    }
    __syncthreads();
#pragma unroll
    for (int kk = 0; kk < 2; kk++) {
      bf16x8 af[4], bfr[4];
#pragma unroll
      for (int mi = 0; mi < 4; mi++) af[mi] = *(const bf16x8*)(As + (wm + mi * 16 + fr) * 64 + kk * 32 + fg * 8);
#pragma unroll
      for (int ni = 0; ni < 4; ni++) bfr[ni] = *(const bf16x8*)(Bs + (wn + ni * 16 + fr) * 64 + kk * 32 + fg * 8);
#pragma unroll
      for (int mi = 0; mi < 4; mi++)
#pragma unroll
        for (int ni = 0; ni < 4; ni++)
          acc[mi][ni] = __builtin_amdgcn_mfma_f32_16x16x32_bf16(af[mi], bfr[ni], acc[mi][ni], 0, 0, 0);
    }
    __syncthreads();
  }
}

// ---------------- QKV projection; z = 0:Q  1:K  2:V ----------------
__global__ __launch_bounds__(256) void qkv_gemm(const bf16* __restrict__ xb, const bf16* __restrict__ wb,
    const float* __restrict__ bq, const float* __restrict__ bk, const float* __restrict__ bv,
    bf16* __restrict__ qb, float* __restrict__ kout, float* __restrict__ vout, bf16* __restrict__ kbf) {
  __shared__ alignas(16) bf16 As[128 * 64];
  __shared__ alignas(16) bf16 Bs[128 * 64];
  f32x4 acc[4][4];
#pragma unroll
  for (int a = 0; a < 4; a++)
#pragma unroll
    for (int b = 0; b < 4; b++) acc[a][b] = (f32x4){0.f, 0.f, 0.f, 0.f};
  const int z = blockIdx.z;
  const int m0 = blockIdx.y * 128, n0 = blockIdx.x * 128;
  gemm128_mainloop(xb, wb + (size_t)z * 4194304, m0, n0, As, Bs, acc);
  const int lane = threadIdx.x & 63, w = threadIdx.x >> 6;
  const int wm = (w >> 1) * 64, wn = (w & 1) * 64, fr = lane & 15, fg = lane >> 4;
  const float* bias = (z == 0) ? bq : (z == 1 ? bk : bv);
#pragma unroll
  for (int ni = 0; ni < 4; ni++) {
    int col = n0 + wn + ni * 16 + fr;
    float bi = bias[col];
#pragma unroll
    for (int mi = 0; mi < 4; mi++) {
#pragma unroll
      for (int r = 0; r < 4; r++) {
        int row = m0 + wm + mi * 16 + fg * 4 + r;
        float v = acc[mi][ni][r] + bi;
        if (z == 0) {
          // fold 1/sqrt(128) * log2(e) so attn can use v_exp_f32 (exp2) directly
          qb[(size_t)row * 2048 + col] = (bf16)(v * 0.12751744955867606f);
        } else {
          size_t co = (((size_t)(row >> 11) * 16 + (col >> 7)) * 4096 + 2048 + (row & 2047)) * 128 + (col & 127);
          if (z == 1) { kout[co] = v; kbf[co] = (bf16)v; }
          else        { vout[co] = v; }
        }
      }
    }
  }
}

// ---------------- V cache -> transposed bf16  [BH][128][4096] ----------------
__global__ __launch_bounds__(256) void build_vt(const float* __restrict__ vsrc, bf16* __restrict__ vtb) {
  __shared__ float tile[64][65];
  const int tid = threadIdx.x;
  const int bh = blockIdx.z;
  const int t0 = blockIdx.x * 64, d0 = blockIdx.y * 64;
  const float* src = vsrc + ((size_t)bh * LT + t0) * HD + d0;
#pragma unroll
  for (int i = 0; i < 4; i++) {
    int idx = i * 256 + tid;
    int rr = idx >> 4, c4 = (idx & 15) * 4;
    float4 v = *(const float4*)(src + rr * HD + c4);
    tile[rr][c4 + 0] = v.x; tile[rr][c4 + 1] = v.y; tile[rr][c4 + 2] = v.z; tile[rr][c4 + 3] = v.w;
  }
  __syncthreads();
  bf16* dst = vtb + (size_t)bh * HD * LT + (size_t)d0 * LT + t0;
#pragma unroll
  for (int i = 0; i < 4; i++) {
    int idx = i * 256 + tid;
    int dr = idx >> 4, c4 = (idx & 15) * 4;
    bf16x4 o = { (bf16)tile[c4 + 0][dr], (bf16)tile[c4 + 1][dr],
                 (bf16)tile[c4 + 2][dr], (bf16)tile[c4 + 3][dr] };
    *(bf16x4*)(dst + (size_t)dr * LT + c4) = o;
  }
}

// ---------------- flash attention: 4 waves x 32 q-rows, KVBLK=64 ----------------
// R4: occupancy fix — SINGLE-buffered K/Vt (dbuf measured ~3% in R2, not worth
//     40 KiB): LDS = 16K(K)+16K(Vt)+16K(P) = 48 KiB -> 3 blocks/CU = 12 waves/CU
//     (was 8). Loop: STAGE; sync; compute; sync. T5 setprio around MFMA clusters.
__global__ __launch_bounds__(256, 3) void attn(const bf16* __restrict__ qb, const bf16* __restrict__ kb,
                                               const bf16* __restrict__ vtb, bf16* __restrict__ ctxb) {
  __shared__ alignas(16) bf16 kbuf[64 * 128];     // [key][d], swizzled
  __shared__ alignas(16) bf16 vtbuf[128 * 64];    // [d][key], swizzled
  __shared__ alignas(16) bf16 pbuf[4][2][16 * 64];// per-wave, per-set [q][key], swizzled
  const int tid = threadIdx.x, lane = tid & 63, w = tid >> 6;   // w in 0..3
  const int fr = lane & 15, fg = lane >> 4;
  const int bh = blockIdx.y, b = bh >> 4;
  const int q0 = blockIdx.x * 128;
  // two 16-row q-sets per wave: rows q0 + w*32 + s*16 + {fr | fg*4+r}
  bf16x8 aq[2][4];
#pragma unroll
  for (int s = 0; s < 2; s++) {
    const bf16* qrow = qb + (size_t)(b * LQ + q0 + w * 32 + s * 16 + fr) * D_MODEL + (bh & 15) * HD;
#pragma unroll
    for (int c = 0; c < 4; c++) aq[s][c] = *(const bf16x8*)(qrow + c * 32 + fg * 8);
  }
  const bf16* Kb = kb + (size_t)bh * LT * HD;
  const bf16* Vt = vtb + (size_t)bh * HD * LT;
  float m_[2][4];
  f32x4 ctx[2][8], sum_[2];
#pragma unroll
  for (int s = 0; s < 2; s++) {
#pragma unroll
    for (int r = 0; r < 4; r++) m_[s][r] = -__builtin_inff();
#pragma unroll
    for (int d = 0; d < 8; d++) ctx[s][d] = (f32x4){0.f, 0.f, 0.f, 0.f};
    sum_[s] = (f32x4){0.f, 0.f, 0.f, 0.f};
  }
  bf16x8 vones;
#pragma unroll
  for (int j = 0; j < 8; j++) vones[j] = (bf16)1.0f;

  // staging: 256 threads, 4 rounds each for K (16 rows/round) and Vt (32 rows/round)
  // inverse-swizzled global source col, linear LDS dest (rule #21)
#define STAGE_KV(k0s)                                                                        \
  do {                                                                                       \
    _Pragma("unroll")                                                                        \
    for (int j = 0; j < 4; j++) {                                                            \
      const int krow = j * 16 + w * 4 + (lane >> 4);                                         \
      const int kscol = ((lane & 15) ^ (krow & 7)) * 8;                                      \
      gload16(Kb + (size_t)((k0s) + krow) * HD + kscol, &kbuf[(j * 16 + w * 4) * HD]);       \
      const int vrw = j * 32 + w * 8 + (lane >> 3);                                          \
      const int vscol = ((lane & 7) ^ (vrw & 7)) * 8;                                        \
      gload16(Vt + (size_t)vrw * LT + (k0s) + vscol, &vtbuf[(j * 32 + w * 8) * 64]);         \
    }                                                                                        \
  } while (0)

  for (int k0 = 0; k0 < LT; k0 += 64) {
    STAGE_KV(k0);
    __syncthreads();                       // vmcnt drained by compiler before barrier
    // S = Q K^T for both q-sets; each kf read feeds 2 MFMAs
    f32x4 sS[2][4];
    __builtin_amdgcn_s_setprio(1);
#pragma unroll
    for (int n = 0; n < 4; n++) {
      sS[0][n] = (f32x4){0.f, 0.f, 0.f, 0.f};
      sS[1][n] = (f32x4){0.f, 0.f, 0.f, 0.f};
#pragma unroll
      for (int c = 0; c < 4; c++) {
        bf16x8 kf = *(const bf16x8*)(kbuf + (n * 16 + fr) * HD + (((c * 4 + fg) ^ (fr & 7)) * 8));
        sS[0][n] = __builtin_amdgcn_mfma_f32_16x16x32_bf16(aq[0][c], kf, sS[0][n], 0, 0, 0);
        sS[1][n] = __builtin_amdgcn_mfma_f32_16x16x32_bf16(aq[1][c], kf, sS[1][n], 0, 0, 0);
      }
    }
    __builtin_amdgcn_s_setprio(0);
    // tile max per row (row q = fg*4+r within set), 4-step shfl over fr group
    float tmax[2][4];
    int ok = 1;
#pragma unroll
    for (int s = 0; s < 2; s++)
#pragma unroll
      for (int r = 0; r < 4; r++) {
        float t = fmaxf(fmaxf(sS[s][0][r], sS[s][1][r]), fmaxf(sS[s][2][r], sS[s][3][r]));
#pragma unroll
        for (int mk = 1; mk <= 8; mk <<= 1) t = fmaxf(t, __shfl_xor(t, mk));
        tmax[s][r] = t;
        ok &= (t <= m_[s][r] + 8.f);
      }
    // defer-max: only rescale when some row's max grew past THR=8 (log2 units)
    if (!__all(ok)) {
#pragma unroll
      for (int s = 0; s < 2; s++)
#pragma unroll
        for (int r = 0; r < 4; r++) {
          float mn = fmaxf(m_[s][r], tmax[s][r]);
          float al = __builtin_amdgcn_exp2f(m_[s][r] - mn);
          m_[s][r] = mn;
#pragma unroll
          for (int d = 0; d < 8; d++) ctx[s][d][r] *= al;
          sum_[s][r] *= al;
        }
    }
    // P = exp2(S - m), write to per-wave LDS (A-frag layout, XOR-swizzled)
#pragma unroll
    for (int s = 0; s < 2; s++) {
      bf16* pw = &pbuf[w][s][0];
#pragma unroll
      for (int n = 0; n < 4; n++) {
        const int gr = n * 2 + (fr >> 3);
#pragma unroll
        for (int r = 0; r < 4; r++) {
          const int row = fg * 4 + r;
          pw[row * 64 + ((gr ^ (row & 7)) * 8) + (fr & 7)] =
              (bf16)__builtin_amdgcn_exp2f(sS[s][n][r] - m_[s][r]);
        }
      }
    }
    // wave-private buffer: in-wave ordering only
    asm volatile("s_waitcnt lgkmcnt(0)" ::: "memory");
    bf16x8 pf[2][2];
#pragma unroll
    for (int s = 0; s < 2; s++) {
      const bf16* pw = &pbuf[w][s][0];
      pf[s][0] = *(const bf16x8*)(pw + fr * 64 + ((fg ^ (fr & 7)) * 8));
      pf[s][1] = *(const bf16x8*)(pw + fr * 64 + (((4 + fg) ^ (fr & 7)) * 8));
    }
    // PV: each v fragment feeds both q-sets
    __builtin_amdgcn_s_setprio(1);
#pragma unroll
    for (int d = 0; d < 8; d++) {
      bf16x8 v0 = *(const bf16x8*)(vtbuf + (d * 16 + fr) * 64 + ((fg ^ (fr & 7)) * 8));
      ctx[0][d] = __builtin_amdgcn_mfma_f32_16x16x32_bf16(pf[0][0], v0, ctx[0][d], 0, 0, 0);
      ctx[1][d] = __builtin_amdgcn_mfma_f32_16x16x32_bf16(pf[1][0], v0, ctx[1][d], 0, 0, 0);
      bf16x8 v1 = *(const bf16x8*)(vtbuf + (d * 16 + fr) * 64 + (((4 + fg) ^ (fr & 7)) * 8));
      ctx[0][d] = __builtin_amdgcn_mfma_f32_16x16x32_bf16(pf[0][1], v1, ctx[0][d], 0, 0, 0);
      ctx[1][d] = __builtin_amdgcn_mfma_f32_16x16x32_bf16(pf[1][1], v1, ctx[1][d], 0, 0, 0);
    }
    // denominator via MFMA against all-ones B: every output col = row-sum of P
#pragma unroll
    for (int s = 0; s < 2; s++) {
      sum_[s] = __builtin_amdgcn_mfma_f32_16x16x32_bf16(pf[s][0], vones, sum_[s], 0, 0, 0);
      sum_[s] = __builtin_amdgcn_mfma_f32_16x16x32_bf16(pf[s][1], vones, sum_[s], 0, 0, 0);
    }
    __builtin_amdgcn_s_setprio(0);
    __syncthreads();                       // all reads done before next STAGE overwrites
  }
#undef STAGE_KV
#pragma unroll
  for (int s = 0; s < 2; s++) {
    float inv[4];
#pragma unroll
    for (int r = 0; r < 4; r++) inv[r] = 1.f / sum_[s][r];
    bf16* crow = ctxb + (size_t)(b * LQ + q0 + w * 32 + s * 16 + fg * 4) * D_MODEL + (bh & 15) * HD + fr;
#pragma unroll
    for (int r = 0; r < 4; r++)
#pragma unroll
      for (int d = 0; d < 8; d++)
        crow[(size_t)r * D_MODEL + d * 16] = (bf16)(ctx[s][d][r] * inv[r]);
  }
}

// ---------------- output projection ----------------
__global__ __launch_bounds__(256) void out_gemm(const bf16* __restrict__ cb, const bf16* __restrict__ wo,
                                                const float* __restrict__ bo, float* __restrict__ out) {
  __shared__ alignas(16) bf16 As[128 * 64];
  __shared__ alignas(16) bf16 Bs[128 * 64];
  f32x4 acc[4][4];
#pragma unroll
  for (int a = 0; a < 4; a++)
#pragma unroll
    for (int b = 0; b < 4; b++) acc[a][b] = (f32x4){0.f, 0.f, 0.f, 0.f};
  const int m0 = blockIdx.y * 128, n0 = blockIdx.x * 128;
  gemm128_mainloop(cb, wo, m0, n0, As, Bs, acc);
  const int lane = threadIdx.x & 63, w = threadIdx.x >> 6;
  const int wm = (w >> 1) * 64, wn = (w & 1) * 64, fr = lane & 15, fg = lane >> 4;
#pragma unroll
  for (int ni = 0; ni < 4; ni++) {
    int col = n0 + wn + ni * 16 + fr;
    float bi = bo[col];
#pragma unroll
    for (int mi = 0; mi < 4; mi++)
#pragma unroll
      for (int r = 0; r < 4; r++) {
        int row = m0 + wm + mi * 16 + fg * 4 + r;
        out[(size_t)row * 2048 + col] = acc[mi][ni][r] + bi;
      }
  }
}

extern "C" void kernel_launch(void* const* d_in, const int* in_sizes, int n_in,
                              void* d_out, int out_size, void* d_ws, size_t ws_size,
                              hipStream_t stream) {
  const float* x  = (const float*)d_in[0];
  const float* pk = (const float*)d_in[1];
  const float* pv = (const float*)d_in[2];
  const float* Wq = (const float*)d_in[3];
  const float* bq = (const float*)d_in[4];
  const float* Wk = (const float*)d_in[5];
  const float* bk = (const float*)d_in[6];
  const float* Wv = (const float*)d_in[7];
  const float* bv = (const float*)d_in[8];
  const float* Wo = (const float*)d_in[9];
  const float* bo = (const float*)d_in[10];

  float* out  = (float*)d_out;
  float* kout = out + 8388608;   // B*L*D
  float* vout = out + 25165824;

  char* p = (char*)d_ws;
  bf16* xb  = (bf16*)p;                   // 16 MiB, reused as ctxb after QKV gemm
  bf16* wb  = (bf16*)(p + 16777216);      // 32 MiB: Wq,Wk,Wv,Wo bf16
  bf16* qb  = (bf16*)(p + 50331648);      // 16 MiB (pre-scaled Q)
  bf16* kbf = (bf16*)(p + 67108864);      // 32 MiB K cache bf16 [BH][4096][128]
  bf16* vtb = (bf16*)(p + 100663296);     // 32 MiB V^T cache bf16 [BH][128][4096]
  bf16* ctxb = xb;

  conv_bf16<<<8192, 256, 0, stream>>>(x, xb, 8388608);
  conv_bf16<<<4096, 256, 0, stream>>>(Wq, wb,            4194304);
  conv_bf16<<<4096, 256, 0, stream>>>(Wk, wb + 4194304,  4194304);
  conv_bf16<<<4096, 256, 0, stream>>>(Wv, wb + 8388608,  4194304);
  conv_bf16<<<4096, 256, 0, stream>>>(Wo, wb + 12582912, 4194304);
  copy_past<<<8192, 256, 0, stream>>>(pk, kout, kbf);
  copy_past<<<8192, 256, 0, stream>>>(pv, vout, nullptr);

  qkv_gemm<<<dim3(16, 32, 3), 256, 0, stream>>>(xb, wb, bq, bk, bv, qb, kout, vout, kbf);
  build_vt<<<dim3(64, 2, 32), 256, 0, stream>>>(vout, vtb);
  attn<<<dim3(16, 32), 256, 0, stream>>>(qb, kbf, vtb, ctxb);
  out_gemm<<<dim3(16, 32), 256, 0, stream>>>(ctxb, wb + 12582912, bo, out);
}

// Round 6
// 540.352 us; speedup vs baseline: 1.4768x; 1.4768x over previous
//
#include <hip/hip_runtime.h>
#include <cstdint>
#include <cstddef>

typedef __bf16 bf16;
typedef __bf16 bf16x8 __attribute__((ext_vector_type(8)));
typedef __bf16 bf16x4 __attribute__((ext_vector_type(4)));
typedef float f32x4 __attribute__((ext_vector_type(4)));

#define D_MODEL 2048
#define NH 16
#define HD 128
#define LQ 2048
#define LT 4096

__device__ __forceinline__ void gload16(const void* g, void* l) {
  __builtin_amdgcn_global_load_lds((const __attribute__((address_space(1))) void*)g,
                                   (__attribute__((address_space(3))) void*)l, 16, 0, 0);
}

// ---------------- elementwise fp32 -> bf16 ----------------
__global__ __launch_bounds__(256) void conv_bf16(const float* __restrict__ s, bf16* __restrict__ d, int n) {
  int i = (blockIdx.x * 256 + threadIdx.x) * 4;
  if (i >= n) return;
  float4 v = *(const float4*)(s + i);
  bf16x4 o = { (bf16)v.x, (bf16)v.y, (bf16)v.z, (bf16)v.w };
  *(bf16x4*)(d + i) = o;
}

// ---------------- copy past K/V into cache (fp32 out, optional bf16) ----------------
// src layout [BH][2048][128]; dst layout [BH][4096][128] rows 0..2047
__global__ __launch_bounds__(256) void copy_past(const float* __restrict__ src, float* __restrict__ dstf,
                                                 bf16* __restrict__ dstb) {
  int i = (blockIdx.x * 256 + threadIdx.x) * 4;
  int bh = i >> 18;          // / (2048*128)
  int rem = i & 262143;
  size_t o = ((size_t)bh << 19) + rem;   // * (4096*128)
  float4 v = *(const float4*)(src + i);
  *(float4*)(dstf + o) = v;
  if (dstb) {
    bf16x4 ob = { (bf16)v.x, (bf16)v.y, (bf16)v.z, (bf16)v.w };
    *(bf16x4*)(dstb + o) = ob;
  }
}

// ---------------- shared 128x128 bf16 GEMM mainloop (C = A * B^T), K = 2048 ----------------
__device__ __forceinline__ void gemm128_mainloop(const bf16* __restrict__ A, const bf16* __restrict__ B,
                                                 int m0, int n0, bf16* As, bf16* Bs, f32x4 (&acc)[4][4]) {
  const int tid = threadIdx.x, lane = tid & 63, w = tid >> 6;
  const int srow = w * 8 + (lane >> 3), scol = (lane & 7) * 8;
  const int wm = (w >> 1) * 64, wn = (w & 1) * 64, fr = lane & 15, fg = lane >> 4;
  for (int k0 = 0; k0 < 2048; k0 += 64) {
#pragma unroll
    for (int i = 0; i < 4; i++) {
      gload16(A + (size_t)(m0 + i * 32 + srow) * 2048 + k0 + scol, As + (i * 32 + w * 8) * 64);
      gload16(B + (size_t)(n0 + i * 32 + srow) * 2048 + k0 + scol, Bs + (i * 32 + w * 8) * 64);
    }
    __syncthreads();
#pragma unroll
    for (int kk = 0; kk < 2; kk++) {
      bf16x8 af[4], bfr[4];
#pragma unroll
      for (int mi = 0; mi < 4; mi++) af[mi] = *(const bf16x8*)(As + (wm + mi * 16 + fr) * 64 + kk * 32 + fg * 8);
#pragma unroll
      for (int ni = 0; ni < 4; ni++) bfr[ni] = *(const bf16x8*)(Bs + (wn + ni * 16 + fr) * 64 + kk * 32 + fg * 8);
#pragma unroll
      for (int mi = 0; mi < 4; mi++)
#pragma unroll
        for (int ni = 0; ni < 4; ni++)
          acc[mi][ni] = __builtin_amdgcn_mfma_f32_16x16x32_bf16(af[mi], bfr[ni], acc[mi][ni], 0, 0, 0);
    }
    __syncthreads();
  }
}

// ---------------- QKV projection; z = 0:Q  1:K  2:V ----------------
__global__ __launch_bounds__(256) void qkv_gemm(const bf16* __restrict__ xb, const bf16* __restrict__ wb,
    const float* __restrict__ bq, const float* __restrict__ bk, const float* __restrict__ bv,
    bf16* __restrict__ qb, float* __restrict__ kout, float* __restrict__ vout, bf16* __restrict__ kbf) {
  __shared__ alignas(16) bf16 As[128 * 64];
  __shared__ alignas(16) bf16 Bs[128 * 64];
  f32x4 acc[4][4];
#pragma unroll
  for (int a = 0; a < 4; a++)
#pragma unroll
    for (int b = 0; b < 4; b++) acc[a][b] = (f32x4){0.f, 0.f, 0.f, 0.f};
  const int z = blockIdx.z;
  const int m0 = blockIdx.y * 128, n0 = blockIdx.x * 128;
  gemm128_mainloop(xb, wb + (size_t)z * 4194304, m0, n0, As, Bs, acc);
  const int lane = threadIdx.x & 63, w = threadIdx.x >> 6;
  const int wm = (w >> 1) * 64, wn = (w & 1) * 64, fr = lane & 15, fg = lane >> 4;
  const float* bias = (z == 0) ? bq : (z == 1 ? bk : bv);
#pragma unroll
  for (int ni = 0; ni < 4; ni++) {
    int col = n0 + wn + ni * 16 + fr;
    float bi = bias[col];
#pragma unroll
    for (int mi = 0; mi < 4; mi++) {
#pragma unroll
      for (int r = 0; r < 4; r++) {
        int row = m0 + wm + mi * 16 + fg * 4 + r;
        float v = acc[mi][ni][r] + bi;
        if (z == 0) {
          // fold 1/sqrt(128) * log2(e) so attn can use v_exp_f32 (exp2) directly
          qb[(size_t)row * 2048 + col] = (bf16)(v * 0.12751744955867606f);
        } else {
          size_t co = (((size_t)(row >> 11) * 16 + (col >> 7)) * 4096 + 2048 + (row & 2047)) * 128 + (col & 127);
          if (z == 1) { kout[co] = v; kbf[co] = (bf16)v; }
          else        { vout[co] = v; }
        }
      }
    }
  }
}

// ---------------- V cache -> transposed bf16  [BH][128][4096] ----------------
__global__ __launch_bounds__(256) void build_vt(const float* __restrict__ vsrc, bf16* __restrict__ vtb) {
  __shared__ float tile[64][65];
  const int tid = threadIdx.x;
  const int bh = blockIdx.z;
  const int t0 = blockIdx.x * 64, d0 = blockIdx.y * 64;
  const float* src = vsrc + ((size_t)bh * LT + t0) * HD + d0;
#pragma unroll
  for (int i = 0; i < 4; i++) {
    int idx = i * 256 + tid;
    int rr = idx >> 4, c4 = (idx & 15) * 4;
    float4 v = *(const float4*)(src + rr * HD + c4);
    tile[rr][c4 + 0] = v.x; tile[rr][c4 + 1] = v.y; tile[rr][c4 + 2] = v.z; tile[rr][c4 + 3] = v.w;
  }
  __syncthreads();
  bf16* dst = vtb + (size_t)bh * HD * LT + (size_t)d0 * LT + t0;
#pragma unroll
  for (int i = 0; i < 4; i++) {
    int idx = i * 256 + tid;
    int dr = idx >> 4, c4 = (idx & 15) * 4;
    bf16x4 o = { (bf16)tile[c4 + 0][dr], (bf16)tile[c4 + 1][dr],
                 (bf16)tile[c4 + 2][dr], (bf16)tile[c4 + 3][dr] };
    *(bf16x4*)(dst + (size_t)dr * LT + c4) = o;
  }
}

// ---------------- flash attention: 4 waves x 32 q-rows, KVBLK=64 ----------------
// R5: REVERT to R3 structure (double-buffered K/Vt, ONE barrier/iter, 80 KiB,
//     2 blocks/CU — grid caps at 2/CU anyway, so dbuf is the right spend of LDS;
//     R4's single-buffer exposed staging latency and regressed 2x).
//     Additions kept/added on top: T5 setprio around MFMA clusters; bh-grouped
//     block swizzle so each XCD's L2 sees 4 heads (8 MB) instead of 32 (64 MB).
__global__ __launch_bounds__(256, 2) void attn(const bf16* __restrict__ qb, const bf16* __restrict__ kb,
                                               const bf16* __restrict__ vtb, bf16* __restrict__ ctxb) {
  __shared__ alignas(16) bf16 kbuf[2][64 * 128];    // [key][d], swizzled
  __shared__ alignas(16) bf16 vtbuf[2][128 * 64];   // [d][key], swizzled
  __shared__ alignas(16) bf16 pbuf[4][2][16 * 64];  // per-wave, per-set [q][key], swizzled
  const int tid = threadIdx.x, lane = tid & 63, w = tid >> 6;   // w in 0..3
  const int fr = lane & 15, fg = lane >> 4;
  // bh-grouped swizzle: linear id i -> XCD i&7 handles heads {4*(i&7) .. 4*(i&7)+3}
  const int i_ = blockIdx.x + 16 * blockIdx.y;   // 0..511
  const int j_ = i_ >> 3;
  const int bh = (i_ & 7) * 4 + (j_ & 3);
  const int q0 = (j_ >> 2) * 128;
  const int b = bh >> 4;
  // two 16-row q-sets per wave: rows q0 + w*32 + s*16 + {fr | fg*4+r}
  bf16x8 aq[2][4];
#pragma unroll
  for (int s = 0; s < 2; s++) {
    const bf16* qrow = qb + (size_t)(b * LQ + q0 + w * 32 + s * 16 + fr) * D_MODEL + (bh & 15) * HD;
#pragma unroll
    for (int c = 0; c < 4; c++) aq[s][c] = *(const bf16x8*)(qrow + c * 32 + fg * 8);
  }
  const bf16* Kb = kb + (size_t)bh * LT * HD;
  const bf16* Vt = vtb + (size_t)bh * HD * LT;
  float m_[2][4];
  f32x4 ctx[2][8], sum_[2];
#pragma unroll
  for (int s = 0; s < 2; s++) {
#pragma unroll
    for (int r = 0; r < 4; r++) m_[s][r] = -__builtin_inff();
#pragma unroll
    for (int d = 0; d < 8; d++) ctx[s][d] = (f32x4){0.f, 0.f, 0.f, 0.f};
    sum_[s] = (f32x4){0.f, 0.f, 0.f, 0.f};
  }
  bf16x8 vones;
#pragma unroll
  for (int j = 0; j < 8; j++) vones[j] = (bf16)1.0f;

  // staging: 256 threads, 4 rounds each for K (16 rows/round) and Vt (32 rows/round)
  // inverse-swizzled global source col, linear LDS dest (rule #21)
#define STAGE_KV(k0s, sel)                                                                   \
  do {                                                                                       \
    _Pragma("unroll")                                                                        \
    for (int j = 0; j < 4; j++) {                                                            \
      const int krow = j * 16 + w * 4 + (lane >> 4);                                         \
      const int kscol = ((lane & 15) ^ (krow & 7)) * 8;                                      \
      gload16(Kb + (size_t)((k0s) + krow) * HD + kscol, &kbuf[sel][(j * 16 + w * 4) * HD]);  \
      const int vrw = j * 32 + w * 8 + (lane >> 3);                                          \
      const int vscol = ((lane & 7) ^ (vrw & 7)) * 8;                                        \
      gload16(Vt + (size_t)vrw * LT + (k0s) + vscol, &vtbuf[sel][(j * 32 + w * 8) * 64]);    \
    }                                                                                        \
  } while (0)

  STAGE_KV(0, 0);
  int sel = 0;
  for (int k0 = 0; k0 < LT; k0 += 64) {
    __syncthreads();                       // buf[sel] staged; prev reads of buf[sel^1] done
    const int kn = (k0 + 64) & (LT - 1);   // wrap on last iter (harmless re-stage)
    STAGE_KV(kn, sel ^ 1);                 // overlaps with the whole compute below
    const bf16* kcur = &kbuf[sel][0];
    const bf16* vcur = &vtbuf[sel][0];
    // S = Q K^T for both q-sets; each kf read feeds 2 MFMAs
    f32x4 sS[2][4];
    __builtin_amdgcn_s_setprio(1);
#pragma unroll
    for (int n = 0; n < 4; n++) {
      sS[0][n] = (f32x4){0.f, 0.f, 0.f, 0.f};
      sS[1][n] = (f32x4){0.f, 0.f, 0.f, 0.f};
#pragma unroll
      for (int c = 0; c < 4; c++) {
        bf16x8 kf = *(const bf16x8*)(kcur + (n * 16 + fr) * HD + (((c * 4 + fg) ^ (fr & 7)) * 8));
        sS[0][n] = __builtin_amdgcn_mfma_f32_16x16x32_bf16(aq[0][c], kf, sS[0][n], 0, 0, 0);
        sS[1][n] = __builtin_amdgcn_mfma_f32_16x16x32_bf16(aq[1][c], kf, sS[1][n], 0, 0, 0);
      }
    }
    __builtin_amdgcn_s_setprio(0);
    // tile max per row (row q = fg*4+r within set), 4-step shfl over fr group
    float tmax[2][4];
    int ok = 1;
#pragma unroll
    for (int s = 0; s < 2; s++)
#pragma unroll
      for (int r = 0; r < 4; r++) {
        float t = fmaxf(fmaxf(sS[s][0][r], sS[s][1][r]), fmaxf(sS[s][2][r], sS[s][3][r]));
#pragma unroll
        for (int mk = 1; mk <= 8; mk <<= 1) t = fmaxf(t, __shfl_xor(t, mk));
        tmax[s][r] = t;
        ok &= (t <= m_[s][r] + 8.f);
      }
    // defer-max: only rescale when some row's max grew past THR=8 (log2 units)
    if (!__all(ok)) {
#pragma unroll
      for (int s = 0; s < 2; s++)
#pragma unroll
        for (int r = 0; r < 4; r++) {
          float mn = fmaxf(m_[s][r], tmax[s][r]);
          float al = __builtin_amdgcn_exp2f(m_[s][r] - mn);
          m_[s][r] = mn;
#pragma unroll
          for (int d = 0; d < 8; d++) ctx[s][d][r] *= al;
          sum_[s][r] *= al;
        }
    }
    // P = exp2(S - m), write to per-wave LDS (A-frag layout, XOR-swizzled)
#pragma unroll
    for (int s = 0; s < 2; s++) {
      bf16* pw = &pbuf[w][s][0];
#pragma unroll
      for (int n = 0; n < 4; n++) {
        const int gr = n * 2 + (fr >> 3);
#pragma unroll
        for (int r = 0; r < 4; r++) {
          const int row = fg * 4 + r;
          pw[row * 64 + ((gr ^ (row & 7)) * 8) + (fr & 7)] =
              (bf16)__builtin_amdgcn_exp2f(sS[s][n][r] - m_[s][r]);
        }
      }
    }
    // wave-private buffer: in-wave ordering only
    asm volatile("s_waitcnt lgkmcnt(0)" ::: "memory");
    bf16x8 pf[2][2];
#pragma unroll
    for (int s = 0; s < 2; s++) {
      const bf16* pw = &pbuf[w][s][0];
      pf[s][0] = *(const bf16x8*)(pw + fr * 64 + ((fg ^ (fr & 7)) * 8));
      pf[s][1] = *(const bf16x8*)(pw + fr * 64 + (((4 + fg) ^ (fr & 7)) * 8));
    }
    // PV: each v fragment feeds both q-sets
    __builtin_amdgcn_s_setprio(1);
#pragma unroll
    for (int d = 0; d < 8; d++) {
      bf16x8 v0 = *(const bf16x8*)(vcur + (d * 16 + fr) * 64 + ((fg ^ (fr & 7)) * 8));
      ctx[0][d] = __builtin_amdgcn_mfma_f32_16x16x32_bf16(pf[0][0], v0, ctx[0][d], 0, 0, 0);
      ctx[1][d] = __builtin_amdgcn_mfma_f32_16x16x32_bf16(pf[1][0], v0, ctx[1][d], 0, 0, 0);
      bf16x8 v1 = *(const bf16x8*)(vcur + (d * 16 + fr) * 64 + (((4 + fg) ^ (fr & 7)) * 8));
      ctx[0][d] = __builtin_amdgcn_mfma_f32_16x16x32_bf16(pf[0][1], v1, ctx[0][d], 0, 0, 0);
      ctx[1][d] = __builtin_amdgcn_mfma_f32_16x16x32_bf16(pf[1][1], v1, ctx[1][d], 0, 0, 0);
    }
    // denominator via MFMA against all-ones B: every output col = row-sum of P
#pragma unroll
    for (int s = 0; s < 2; s++) {
      sum_[s] = __builtin_amdgcn_mfma_f32_16x16x32_bf16(pf[s][0], vones, sum_[s], 0, 0, 0);
      sum_[s] = __builtin_amdgcn_mfma_f32_16x16x32_bf16(pf[s][1], vones, sum_[s], 0, 0, 0);
    }
    __builtin_amdgcn_s_setprio(0);
    sel ^= 1;
  }
#undef STAGE_KV
#pragma unroll
  for (int s = 0; s < 2; s++) {
    float inv[4];
#pragma unroll
    for (int r = 0; r < 4; r++) inv[r] = 1.f / sum_[s][r];
    bf16* crow = ctxb + (size_t)(b * LQ + q0 + w * 32 + s * 16 + fg * 4) * D_MODEL + (bh & 15) * HD + fr;
#pragma unroll
    for (int r = 0; r < 4; r++)
#pragma unroll
      for (int d = 0; d < 8; d++)
        crow[(size_t)r * D_MODEL + d * 16] = (bf16)(ctx[s][d][r] * inv[r]);
  }
}

// ---------------- output projection ----------------
__global__ __launch_bounds__(256) void out_gemm(const bf16* __restrict__ cb, const bf16* __restrict__ wo,
                                                const float* __restrict__ bo, float* __restrict__ out) {
  __shared__ alignas(16) bf16 As[128 * 64];
  __shared__ alignas(16) bf16 Bs[128 * 64];
  f32x4 acc[4][4];
#pragma unroll
  for (int a = 0; a < 4; a++)
#pragma unroll
    for (int b = 0; b < 4; b++) acc[a][b] = (f32x4){0.f, 0.f, 0.f, 0.f};
  const int m0 = blockIdx.y * 128, n0 = blockIdx.x * 128;
  gemm128_mainloop(cb, wo, m0, n0, As, Bs, acc);
  const int lane = threadIdx.x & 63, w = threadIdx.x >> 6;
  const int wm = (w >> 1) * 64, wn = (w & 1) * 64, fr = lane & 15, fg = lane >> 4;
#pragma unroll
  for (int ni = 0; ni < 4; ni++) {
    int col = n0 + wn + ni * 16 + fr;
    float bi = bo[col];
#pragma unroll
    for (int mi = 0; mi < 4; mi++)
#pragma unroll
      for (int r = 0; r < 4; r++) {
        int row = m0 + wm + mi * 16 + fg * 4 + r;
        out[(size_t)row * 2048 + col] = acc[mi][ni][r] + bi;
      }
  }
}

extern "C" void kernel_launch(void* const* d_in, const int* in_sizes, int n_in,
                              void* d_out, int out_size, void* d_ws, size_t ws_size,
                              hipStream_t stream) {
  const float* x  = (const float*)d_in[0];
  const float* pk = (const float*)d_in[1];
  const float* pv = (const float*)d_in[2];
  const float* Wq = (const float*)d_in[3];
  const float* bq = (const float*)d_in[4];
  const float* Wk = (const float*)d_in[5];
  const float* bk = (const float*)d_in[6];
  const float* Wv = (const float*)d_in[7];
  const float* bv = (const float*)d_in[8];
  const float* Wo = (const float*)d_in[9];
  const float* bo = (const float*)d_in[10];

  float* out  = (float*)d_out;
  float* kout = out + 8388608;   // B*L*D
  float* vout = out + 25165824;

  char* p = (char*)d_ws;
  bf16* xb  = (bf16*)p;                   // 16 MiB, reused as ctxb after QKV gemm
  bf16* wb  = (bf16*)(p + 16777216);      // 32 MiB: Wq,Wk,Wv,Wo bf16
  bf16* qb  = (bf16*)(p + 50331648);      // 16 MiB (pre-scaled Q)
  bf16* kbf = (bf16*)(p + 67108864);      // 32 MiB K cache bf16 [BH][4096][128]
  bf16* vtb = (bf16*)(p + 100663296);     // 32 MiB V^T cache bf16 [BH][128][4096]
  bf16* ctxb = xb;

  conv_bf16<<<8192, 256, 0, stream>>>(x, xb, 8388608);
  conv_bf16<<<4096, 256, 0, stream>>>(Wq, wb,            4194304);
  conv_bf16<<<4096, 256, 0, stream>>>(Wk, wb + 4194304,  4194304);
  conv_bf16<<<4096, 256, 0, stream>>>(Wv, wb + 8388608,  4194304);
  conv_bf16<<<4096, 256, 0, stream>>>(Wo, wb + 12582912, 4194304);
  copy_past<<<8192, 256, 0, stream>>>(pk, kout, kbf);
  copy_past<<<8192, 256, 0, stream>>>(pv, vout, nullptr);

  qkv_gemm<<<dim3(16, 32, 3), 256, 0, stream>>>(xb, wb, bq, bk, bv, qb, kout, vout, kbf);
  build_vt<<<dim3(64, 2, 32), 256, 0, stream>>>(vout, vtb);
  attn<<<dim3(16, 32), 256, 0, stream>>>(qb, kbf, vtb, ctxb);
  out_gemm<<<dim3(16, 32), 256, 0, stream>>>(ctxb, wb + 12582912, bo, out);
}

// Round 7
// 525.289 us; speedup vs baseline: 1.5192x; 1.0287x over previous
//
#include <hip/hip_runtime.h>
#include <cstdint>
#include <cstddef>

typedef __bf16 bf16;
typedef __bf16 bf16x8 __attribute__((ext_vector_type(8)));
typedef __bf16 bf16x4 __attribute__((ext_vector_type(4)));
typedef float f32x4 __attribute__((ext_vector_type(4)));
typedef unsigned int uint;

#define D_MODEL 2048
#define NH 16
#define HD 128
#define LQ 2048
#define LT 4096

__device__ __forceinline__ void gload16(const void* g, void* l) {
  __builtin_amdgcn_global_load_lds((const __attribute__((address_space(1))) void*)g,
                                   (__attribute__((address_space(3))) void*)l, 16, 0, 0);
}

// max over the 16-lane row via DPP row_ror (VALU pipe, not DS pipe)
__device__ __forceinline__ float rowmax16(float t) {
  int i;
  i = __builtin_amdgcn_update_dpp(0, __float_as_int(t), 0x121, 0xF, 0xF, true);
  t = fmaxf(t, __int_as_float(i));
  i = __builtin_amdgcn_update_dpp(0, __float_as_int(t), 0x122, 0xF, 0xF, true);
  t = fmaxf(t, __int_as_float(i));
  i = __builtin_amdgcn_update_dpp(0, __float_as_int(t), 0x124, 0xF, 0xF, true);
  t = fmaxf(t, __int_as_float(i));
  i = __builtin_amdgcn_update_dpp(0, __float_as_int(t), 0x128, 0xF, 0xF, true);
  t = fmaxf(t, __int_as_float(i));
  return t;
}

// ---------------- elementwise fp32 -> bf16 ----------------
__global__ __launch_bounds__(256) void conv_bf16(const float* __restrict__ s, bf16* __restrict__ d, int n) {
  int i = (blockIdx.x * 256 + threadIdx.x) * 4;
  if (i >= n) return;
  float4 v = *(const float4*)(s + i);
  bf16x4 o = { (bf16)v.x, (bf16)v.y, (bf16)v.z, (bf16)v.w };
  *(bf16x4*)(d + i) = o;
}

// fused 4-weight convert: grid (4096, 4); each y-slice is one 2048x2048 matrix
__global__ __launch_bounds__(256) void conv_w4(const float* __restrict__ a, const float* __restrict__ b,
                                               const float* __restrict__ c, const float* __restrict__ d,
                                               bf16* __restrict__ o) {
  const int z = blockIdx.y;
  const float* s = (z == 0) ? a : (z == 1) ? b : (z == 2) ? c : d;
  int i = (blockIdx.x * 256 + threadIdx.x) * 4;
  float4 v = *(const float4*)(s + i);
  bf16x4 ov = { (bf16)v.x, (bf16)v.y, (bf16)v.z, (bf16)v.w };
  *(bf16x4*)(o + (size_t)z * 4194304 + i) = ov;
}

// ---------------- copy past K/V into cache (fp32 out, optional bf16) ----------------
// src layout [BH][2048][128]; dst layout [BH][4096][128] rows 0..2047
__global__ __launch_bounds__(256) void copy_past(const float* __restrict__ src, float* __restrict__ dstf,
                                                 bf16* __restrict__ dstb) {
  int i = (blockIdx.x * 256 + threadIdx.x) * 4;
  int bh = i >> 18;          // / (2048*128)
  int rem = i & 262143;
  size_t o = ((size_t)bh << 19) + rem;   // * (4096*128)
  float4 v = *(const float4*)(src + i);
  *(float4*)(dstf + o) = v;
  if (dstb) {
    bf16x4 ob = { (bf16)v.x, (bf16)v.y, (bf16)v.z, (bf16)v.w };
    *(bf16x4*)(dstb + o) = ob;
  }
}

// ---------------- shared 128x128 bf16 GEMM mainloop (C = A * B^T), K = 2048 ----------------
__device__ __forceinline__ void gemm128_mainloop(const bf16* __restrict__ A, const bf16* __restrict__ B,
                                                 int m0, int n0, bf16* As, bf16* Bs, f32x4 (&acc)[4][4]) {
  const int tid = threadIdx.x, lane = tid & 63, w = tid >> 6;
  const int srow = w * 8 + (lane >> 3), scol = (lane & 7) * 8;
  const int wm = (w >> 1) * 64, wn = (w & 1) * 64, fr = lane & 15, fg = lane >> 4;
  for (int k0 = 0; k0 < 2048; k0 += 64) {
#pragma unroll
    for (int i = 0; i < 4; i++) {
      gload16(A + (size_t)(m0 + i * 32 + srow) * 2048 + k0 + scol, As + (i * 32 + w * 8) * 64);
      gload16(B + (size_t)(n0 + i * 32 + srow) * 2048 + k0 + scol, Bs + (i * 32 + w * 8) * 64);
    }
    __syncthreads();
#pragma unroll
    for (int kk = 0; kk < 2; kk++) {
      bf16x8 af[4], bfr[4];
#pragma unroll
      for (int mi = 0; mi < 4; mi++) af[mi] = *(const bf16x8*)(As + (wm + mi * 16 + fr) * 64 + kk * 32 + fg * 8);
#pragma unroll
      for (int ni = 0; ni < 4; ni++) bfr[ni] = *(const bf16x8*)(Bs + (wn + ni * 16 + fr) * 64 + kk * 32 + fg * 8);
#pragma unroll
      for (int mi = 0; mi < 4; mi++)
#pragma unroll
        for (int ni = 0; ni < 4; ni++)
          acc[mi][ni] = __builtin_amdgcn_mfma_f32_16x16x32_bf16(af[mi], bfr[ni], acc[mi][ni], 0, 0, 0);
    }
    __syncthreads();
  }
}

// ---------------- QKV projection; z = 0:Q  1:K  2:V ----------------
__global__ __launch_bounds__(256) void qkv_gemm(const bf16* __restrict__ xb, const bf16* __restrict__ wb,
    const float* __restrict__ bq, const float* __restrict__ bk, const float* __restrict__ bv,
    bf16* __restrict__ qb, float* __restrict__ kout, float* __restrict__ vout, bf16* __restrict__ kbf) {
  __shared__ alignas(16) bf16 As[128 * 64];
  __shared__ alignas(16) bf16 Bs[128 * 64];
  f32x4 acc[4][4];
#pragma unroll
  for (int a = 0; a < 4; a++)
#pragma unroll
    for (int b = 0; b < 4; b++) acc[a][b] = (f32x4){0.f, 0.f, 0.f, 0.f};
  const int z = blockIdx.z;
  const int m0 = blockIdx.y * 128, n0 = blockIdx.x * 128;
  gemm128_mainloop(xb, wb + (size_t)z * 4194304, m0, n0, As, Bs, acc);
  const int lane = threadIdx.x & 63, w = threadIdx.x >> 6;
  const int wm = (w >> 1) * 64, wn = (w & 1) * 64, fr = lane & 15, fg = lane >> 4;
  const float* bias = (z == 0) ? bq : (z == 1 ? bk : bv);
#pragma unroll
  for (int ni = 0; ni < 4; ni++) {
    int col = n0 + wn + ni * 16 + fr;
    float bi = bias[col];
#pragma unroll
    for (int mi = 0; mi < 4; mi++) {
#pragma unroll
      for (int r = 0; r < 4; r++) {
        int row = m0 + wm + mi * 16 + fg * 4 + r;
        float v = acc[mi][ni][r] + bi;
        if (z == 0) {
          // fold 1/sqrt(128) * log2(e) so attn can use v_exp_f32 (exp2) directly
          qb[(size_t)row * 2048 + col] = (bf16)(v * 0.12751744955867606f);
        } else {
          size_t co = (((size_t)(row >> 11) * 16 + (col >> 7)) * 4096 + 2048 + (row & 2047)) * 128 + (col & 127);
          if (z == 1) { kout[co] = v; kbf[co] = (bf16)v; }
          else        { vout[co] = v; }
        }
      }
    }
  }
}

// ---------------- V cache -> transposed bf16  [BH][128][4096] ----------------
__global__ __launch_bounds__(256) void build_vt(const float* __restrict__ vsrc, bf16* __restrict__ vtb) {
  __shared__ float tile[64][65];
  const int tid = threadIdx.x;
  const int bh = blockIdx.z;
  const int t0 = blockIdx.x * 64, d0 = blockIdx.y * 64;
  const float* src = vsrc + ((size_t)bh * LT + t0) * HD + d0;
#pragma unroll
  for (int i = 0; i < 4; i++) {
    int idx = i * 256 + tid;
    int rr = idx >> 4, c4 = (idx & 15) * 4;
    float4 v = *(const float4*)(src + rr * HD + c4);
    tile[rr][c4 + 0] = v.x; tile[rr][c4 + 1] = v.y; tile[rr][c4 + 2] = v.z; tile[rr][c4 + 3] = v.w;
  }
  __syncthreads();
  bf16* dst = vtb + (size_t)bh * HD * LT + (size_t)d0 * LT + t0;
#pragma unroll
  for (int i = 0; i < 4; i++) {
    int idx = i * 256 + tid;
    int dr = idx >> 4, c4 = (idx & 15) * 4;
    bf16x4 o = { (bf16)tile[c4 + 0][dr], (bf16)tile[c4 + 1][dr],
                 (bf16)tile[c4 + 2][dr], (bf16)tile[c4 + 3][dr] };
    *(bf16x4*)(dst + (size_t)dr * LT + c4) = o;
  }
}

// ---------------- flash attention: 4 waves x 32 q-rows, KVBLK=64 ----------------
// R6: DS-pipe instruction diet — max-reduce moved to DPP row_ror (VALU),
//     P-writes paired via DPP quad_perm into half as many ds_write_b32.
//     Structure otherwise = R5 (dbuf, 1 barrier/iter, setprio, bh-swizzle).
__global__ __launch_bounds__(256, 2) void attn(const bf16* __restrict__ qb, const bf16* __restrict__ kb,
                                               const bf16* __restrict__ vtb, bf16* __restrict__ ctxb) {
  __shared__ alignas(16) bf16 kbuf[2][64 * 128];    // [key][d], swizzled
  __shared__ alignas(16) bf16 vtbuf[2][128 * 64];   // [d][key], swizzled
  __shared__ alignas(16) bf16 pbuf[4][2][16 * 64];  // per-wave, per-set [q][key], swizzled
  const int tid = threadIdx.x, lane = tid & 63, w = tid >> 6;   // w in 0..3
  const int fr = lane & 15, fg = lane >> 4;
  // bh-grouped swizzle: linear id i -> XCD i&7 handles heads {4*(i&7) .. 4*(i&7)+3}
  const int i_ = blockIdx.x + 16 * blockIdx.y;   // 0..511
  const int j_ = i_ >> 3;
  const int bh = (i_ & 7) * 4 + (j_ & 3);
  const int q0 = (j_ >> 2) * 128;
  const int b = bh >> 4;
  // two 16-row q-sets per wave: rows q0 + w*32 + s*16 + {fr | fg*4+r}
  bf16x8 aq[2][4];
#pragma unroll
  for (int s = 0; s < 2; s++) {
    const bf16* qrow = qb + (size_t)(b * LQ + q0 + w * 32 + s * 16 + fr) * D_MODEL + (bh & 15) * HD;
#pragma unroll
    for (int c = 0; c < 4; c++) aq[s][c] = *(const bf16x8*)(qrow + c * 32 + fg * 8);
  }
  const bf16* Kb = kb + (size_t)bh * LT * HD;
  const bf16* Vt = vtb + (size_t)bh * HD * LT;
  float m_[2][4];
  f32x4 ctx[2][8], sum_[2];
#pragma unroll
  for (int s = 0; s < 2; s++) {
#pragma unroll
    for (int r = 0; r < 4; r++) m_[s][r] = -__builtin_inff();
#pragma unroll
    for (int d = 0; d < 8; d++) ctx[s][d] = (f32x4){0.f, 0.f, 0.f, 0.f};
    sum_[s] = (f32x4){0.f, 0.f, 0.f, 0.f};
  }
  bf16x8 vones;
#pragma unroll
  for (int j = 0; j < 8; j++) vones[j] = (bf16)1.0f;

  // staging: 256 threads, 4 rounds each for K (16 rows/round) and Vt (32 rows/round)
  // inverse-swizzled global source col, linear LDS dest (rule #21)
#define STAGE_KV(k0s, sel)                                                                   \
  do {                                                                                       \
    _Pragma("unroll")                                                                        \
    for (int j = 0; j < 4; j++) {                                                            \
      const int krow = j * 16 + w * 4 + (lane >> 4);                                         \
      const int kscol = ((lane & 15) ^ (krow & 7)) * 8;                                      \
      gload16(Kb + (size_t)((k0s) + krow) * HD + kscol, &kbuf[sel][(j * 16 + w * 4) * HD]);  \
      const int vrw = j * 32 + w * 8 + (lane >> 3);                                          \
      const int vscol = ((lane & 7) ^ (vrw & 7)) * 8;                                        \
      gload16(Vt + (size_t)vrw * LT + (k0s) + vscol, &vtbuf[sel][(j * 32 + w * 8) * 64]);    \
    }                                                                                        \
  } while (0)

  STAGE_KV(0, 0);
  int sel = 0;
  for (int k0 = 0; k0 < LT; k0 += 64) {
    __syncthreads();                       // buf[sel] staged; prev reads of buf[sel^1] done
    const int kn = (k0 + 64) & (LT - 1);   // wrap on last iter (harmless re-stage)
    STAGE_KV(kn, sel ^ 1);                 // overlaps with the whole compute below
    const bf16* kcur = &kbuf[sel][0];
    const bf16* vcur = &vtbuf[sel][0];
    // S = Q K^T for both q-sets; each kf read feeds 2 MFMAs
    f32x4 sS[2][4];
    __builtin_amdgcn_s_setprio(1);
#pragma unroll
    for (int n = 0; n < 4; n++) {
      sS[0][n] = (f32x4){0.f, 0.f, 0.f, 0.f};
      sS[1][n] = (f32x4){0.f, 0.f, 0.f, 0.f};
#pragma unroll
      for (int c = 0; c < 4; c++) {
        bf16x8 kf = *(const bf16x8*)(kcur + (n * 16 + fr) * HD + (((c * 4 + fg) ^ (fr & 7)) * 8));
        sS[0][n] = __builtin_amdgcn_mfma_f32_16x16x32_bf16(aq[0][c], kf, sS[0][n], 0, 0, 0);
        sS[1][n] = __builtin_amdgcn_mfma_f32_16x16x32_bf16(aq[1][c], kf, sS[1][n], 0, 0, 0);
      }
    }
    __builtin_amdgcn_s_setprio(0);
    // tile max per row (row q = fg*4+r within set), DPP rotate-reduce over 16-lane row
    float tmax[2][4];
    int ok = 1;
#pragma unroll
    for (int s = 0; s < 2; s++)
#pragma unroll
      for (int r = 0; r < 4; r++) {
        float t = fmaxf(fmaxf(sS[s][0][r], sS[s][1][r]), fmaxf(sS[s][2][r], sS[s][3][r]));
        t = rowmax16(t);
        tmax[s][r] = t;
        ok &= (t <= m_[s][r] + 8.f);
      }
    // defer-max: only rescale when some row's max grew past THR=8 (log2 units)
    if (!__all(ok)) {
#pragma unroll
      for (int s = 0; s < 2; s++)
#pragma unroll
        for (int r = 0; r < 4; r++) {
          float mn = fmaxf(m_[s][r], tmax[s][r]);
          float al = __builtin_amdgcn_exp2f(m_[s][r] - mn);
          m_[s][r] = mn;
#pragma unroll
          for (int d = 0; d < 8; d++) ctx[s][d][r] *= al;
          sum_[s][r] *= al;
        }
    }
    // P = exp2(S - m) -> per-wave LDS. Pair lanes via DPP quad_perm(1,0,3,2):
    // even-fr lanes write rows R+0,R+1 dwords; odd-fr rows R+2,R+3 -> 2 b32/ (s,n)
    {
      const int odd = fr & 1;
      const int ce = fr & ~1;
      const int rowA = fg * 4 + (odd ? 2 : 0);
      const int rowB = rowA + 1;
#pragma unroll
      for (int s = 0; s < 2; s++) {
        bf16* pw = &pbuf[w][s][0];
#pragma unroll
        for (int n = 0; n < 4; n++) {
          const int gr = n * 2 + (fr >> 3);
          uint bb[4], pp[4];
#pragma unroll
          for (int r = 0; r < 4; r++) {
            bf16 h = (bf16)__builtin_amdgcn_exp2f(sS[s][n][r] - m_[s][r]);
            unsigned short us;
            __builtin_memcpy(&us, &h, 2);
            bb[r] = us;
          }
#pragma unroll
          for (int r = 0; r < 4; r++)
            pp[r] = (uint)__builtin_amdgcn_update_dpp(0, (int)bb[r], 0xB1, 0xF, 0xF, true);
          uint d0 = odd ? (pp[2] | (bb[2] << 16)) : (bb[0] | (pp[0] << 16));
          uint d1 = odd ? (pp[3] | (bb[3] << 16)) : (bb[1] | (pp[1] << 16));
          *(uint*)&pw[rowA * 64 + ((gr ^ (rowA & 7)) * 8) + (ce & 7)] = d0;
          *(uint*)&pw[rowB * 64 + ((gr ^ (rowB & 7)) * 8) + (ce & 7)] = d1;
        }
      }
    }
    // wave-private buffer: in-wave ordering only
    asm volatile("s_waitcnt lgkmcnt(0)" ::: "memory");
    bf16x8 pf[2][2];
#pragma unroll
    for (int s = 0; s < 2; s++) {
      const bf16* pw = &pbuf[w][s][0];
      pf[s][0] = *(const bf16x8*)(pw + fr * 64 + ((fg ^ (fr & 7)) * 8));
      pf[s][1] = *(const bf16x8*)(pw + fr * 64 + (((4 + fg) ^ (fr & 7)) * 8));
    }
    // PV: each v fragment feeds both q-sets
    __builtin_amdgcn_s_setprio(1);
#pragma unroll
    for (int d = 0; d < 8; d++) {
      bf16x8 v0 = *(const bf16x8*)(vcur + (d * 16 + fr) * 64 + ((fg ^ (fr & 7)) * 8));
      ctx[0][d] = __builtin_amdgcn_mfma_f32_16x16x32_bf16(pf[0][0], v0, ctx[0][d], 0, 0, 0);
      ctx[1][d] = __builtin_amdgcn_mfma_f32_16x16x32_bf16(pf[1][0], v0, ctx[1][d], 0, 0, 0);
      bf16x8 v1 = *(const bf16x8*)(vcur + (d * 16 + fr) * 64 + (((4 + fg) ^ (fr & 7)) * 8));
      ctx[0][d] = __builtin_amdgcn_mfma_f32_16x16x32_bf16(pf[0][1], v1, ctx[0][d], 0, 0, 0);
      ctx[1][d] = __builtin_amdgcn_mfma_f32_16x16x32_bf16(pf[1][1], v1, ctx[1][d], 0, 0, 0);
    }
    // denominator via MFMA against all-ones B: every output col = row-sum of P
#pragma unroll
    for (int s = 0; s < 2; s++) {
      sum_[s] = __builtin_amdgcn_mfma_f32_16x16x32_bf16(pf[s][0], vones, sum_[s], 0, 0, 0);
      sum_[s] = __builtin_amdgcn_mfma_f32_16x16x32_bf16(pf[s][1], vones, sum_[s], 0, 0, 0);
    }
    __builtin_amdgcn_s_setprio(0);
    sel ^= 1;
  }
#undef STAGE_KV
#pragma unroll
  for (int s = 0; s < 2; s++) {
    float inv[4];
#pragma unroll
    for (int r = 0; r < 4; r++) inv[r] = 1.f / sum_[s][r];
    bf16* crow = ctxb + (size_t)(b * LQ + q0 + w * 32 + s * 16 + fg * 4) * D_MODEL + (bh & 15) * HD + fr;
#pragma unroll
    for (int r = 0; r < 4; r++)
#pragma unroll
      for (int d = 0; d < 8; d++)
        crow[(size_t)r * D_MODEL + d * 16] = (bf16)(ctx[s][d][r] * inv[r]);
  }
}

// ---------------- output projection ----------------
__global__ __launch_bounds__(256) void out_gemm(const bf16* __restrict__ cb, const bf16* __restrict__ wo,
                                                const float* __restrict__ bo, float* __restrict__ out) {
  __shared__ alignas(16) bf16 As[128 * 64];
  __shared__ alignas(16) bf16 Bs[128 * 64];
  f32x4 acc[4][4];
#pragma unroll
  for (int a = 0; a < 4; a++)
#pragma unroll
    for (int b = 0; b < 4; b++) acc[a][b] = (f32x4){0.f, 0.f, 0.f, 0.f};
  const int m0 = blockIdx.y * 128, n0 = blockIdx.x * 128;
  gemm128_mainloop(cb, wo, m0, n0, As, Bs, acc);
  const int lane = threadIdx.x & 63, w = threadIdx.x >> 6;
  const int wm = (w >> 1) * 64, wn = (w & 1) * 64, fr = lane & 15, fg = lane >> 4;
#pragma unroll
  for (int ni = 0; ni < 4; ni++) {
    int col = n0 + wn + ni * 16 + fr;
    float bi = bo[col];
#pragma unroll
    for (int mi = 0; mi < 4; mi++)
#pragma unroll
      for (int r = 0; r < 4; r++) {
        int row = m0 + wm + mi * 16 + fg * 4 + r;
        out[(size_t)row * 2048 + col] = acc[mi][ni][r] + bi;
      }
  }
}

extern "C" void kernel_launch(void* const* d_in, const int* in_sizes, int n_in,
                              void* d_out, int out_size, void* d_ws, size_t ws_size,
                              hipStream_t stream) {
  const float* x  = (const float*)d_in[0];
  const float* pk = (const float*)d_in[1];
  const float* pv = (const float*)d_in[2];
  const float* Wq = (const float*)d_in[3];
  const float* bq = (const float*)d_in[4];
  const float* Wk = (const float*)d_in[5];
  const float* bk = (const float*)d_in[6];
  const float* Wv = (const float*)d_in[7];
  const float* bv = (const float*)d_in[8];
  const float* Wo = (const float*)d_in[9];
  const float* bo = (const float*)d_in[10];

  float* out  = (float*)d_out;
  float* kout = out + 8388608;   // B*L*D
  float* vout = out + 25165824;

  char* p = (char*)d_ws;
  bf16* xb  = (bf16*)p;                   // 16 MiB, reused as ctxb after QKV gemm
  bf16* wb  = (bf16*)(p + 16777216);      // 32 MiB: Wq,Wk,Wv,Wo bf16
  bf16* qb  = (bf16*)(p + 50331648);      // 16 MiB (pre-scaled Q)
  bf16* kbf = (bf16*)(p + 67108864);      // 32 MiB K cache bf16 [BH][4096][128]
  bf16* vtb = (bf16*)(p + 100663296);     // 32 MiB V^T cache bf16 [BH][128][4096]
  bf16* ctxb = xb;

  conv_bf16<<<8192, 256, 0, stream>>>(x, xb, 8388608);
  conv_w4<<<dim3(4096, 4), 256, 0, stream>>>(Wq, Wk, Wv, Wo, wb);
  copy_past<<<8192, 256, 0, stream>>>(pk, kout, kbf);
  copy_past<<<8192, 256, 0, stream>>>(pv, vout, nullptr);

  qkv_gemm<<<dim3(16, 32, 3), 256, 0, stream>>>(xb, wb, bq, bk, bv, qb, kout, vout, kbf);
  build_vt<<<dim3(64, 2, 32), 256, 0, stream>>>(vout, vtb);
  attn<<<dim3(16, 32), 256, 0, stream>>>(qb, kbf, vtb, ctxb);
  out_gemm<<<dim3(16, 32), 256, 0, stream>>>(ctxb, wb + 12582912, bo, out);
}

// Round 8
// 497.771 us; speedup vs baseline: 1.6032x; 1.0553x over previous
//
#include <hip/hip_runtime.h>
#include <cstdint>
#include <cstddef>

typedef __bf16 bf16;
typedef __bf16 bf16x8 __attribute__((ext_vector_type(8)));
typedef __bf16 bf16x4 __attribute__((ext_vector_type(4)));
typedef float f32x4 __attribute__((ext_vector_type(4)));
typedef unsigned int uint;

#define D_MODEL 2048
#define NH 16
#define HD 128
#define LQ 2048
#define LT 4096

__device__ __forceinline__ void gload16(const void* g, void* l) {
  __builtin_amdgcn_global_load_lds((const __attribute__((address_space(1))) void*)g,
                                   (__attribute__((address_space(3))) void*)l, 16, 0, 0);
}

// max over the 16-lane row via DPP row_ror (VALU pipe, not DS pipe)
__device__ __forceinline__ float rowmax16(float t) {
  int i;
  i = __builtin_amdgcn_update_dpp(0, __float_as_int(t), 0x121, 0xF, 0xF, true);
  t = fmaxf(t, __int_as_float(i));
  i = __builtin_amdgcn_update_dpp(0, __float_as_int(t), 0x122, 0xF, 0xF, true);
  t = fmaxf(t, __int_as_float(i));
  i = __builtin_amdgcn_update_dpp(0, __float_as_int(t), 0x124, 0xF, 0xF, true);
  t = fmaxf(t, __int_as_float(i));
  i = __builtin_amdgcn_update_dpp(0, __float_as_int(t), 0x128, 0xF, 0xF, true);
  t = fmaxf(t, __int_as_float(i));
  return t;
}

// ---------------- elementwise fp32 -> bf16 ----------------
__global__ __launch_bounds__(256) void conv_bf16(const float* __restrict__ s, bf16* __restrict__ d, int n) {
  int i = (blockIdx.x * 256 + threadIdx.x) * 4;
  if (i >= n) return;
  float4 v = *(const float4*)(s + i);
  bf16x4 o = { (bf16)v.x, (bf16)v.y, (bf16)v.z, (bf16)v.w };
  *(bf16x4*)(d + i) = o;
}

// fused 4-weight convert: grid (4096, 4); each y-slice is one 2048x2048 matrix
__global__ __launch_bounds__(256) void conv_w4(const float* __restrict__ a, const float* __restrict__ b,
                                               const float* __restrict__ c, const float* __restrict__ d,
                                               bf16* __restrict__ o) {
  const int z = blockIdx.y;
  const float* s = (z == 0) ? a : (z == 1) ? b : (z == 2) ? c : d;
  int i = (blockIdx.x * 256 + threadIdx.x) * 4;
  float4 v = *(const float4*)(s + i);
  bf16x4 ov = { (bf16)v.x, (bf16)v.y, (bf16)v.z, (bf16)v.w };
  *(bf16x4*)(o + (size_t)z * 4194304 + i) = ov;
}

// ---------------- copy past K/V into cache (fp32 out, optional bf16) ----------------
// src layout [BH][2048][128]; dst layout [BH][4096][128] rows 0..2047
__global__ __launch_bounds__(256) void copy_past(const float* __restrict__ src, float* __restrict__ dstf,
                                                 bf16* __restrict__ dstb) {
  int i = (blockIdx.x * 256 + threadIdx.x) * 4;
  int bh = i >> 18;          // / (2048*128)
  int rem = i & 262143;
  size_t o = ((size_t)bh << 19) + rem;   // * (4096*128)
  float4 v = *(const float4*)(src + i);
  *(float4*)(dstf + o) = v;
  if (dstb) {
    bf16x4 ob = { (bf16)v.x, (bf16)v.y, (bf16)v.z, (bf16)v.w };
    *(bf16x4*)(dstb + o) = ob;
  }
}

// ---------------- shared 128x128 bf16 GEMM mainloop (C = A * B^T), K = 2048 ----------------
__device__ __forceinline__ void gemm128_mainloop(const bf16* __restrict__ A, const bf16* __restrict__ B,
                                                 int m0, int n0, bf16* As, bf16* Bs, f32x4 (&acc)[4][4]) {
  const int tid = threadIdx.x, lane = tid & 63, w = tid >> 6;
  const int srow = w * 8 + (lane >> 3), scol = (lane & 7) * 8;
  const int wm = (w >> 1) * 64, wn = (w & 1) * 64, fr = lane & 15, fg = lane >> 4;
  for (int k0 = 0; k0 < 2048; k0 += 64) {
#pragma unroll
    for (int i = 0; i < 4; i++) {
      gload16(A + (size_t)(m0 + i * 32 + srow) * 2048 + k0 + scol, As + (i * 32 + w * 8) * 64);
      gload16(B + (size_t)(n0 + i * 32 + srow) * 2048 + k0 + scol, Bs + (i * 32 + w * 8) * 64);
    }
    __syncthreads();
#pragma unroll
    for (int kk = 0; kk < 2; kk++) {
      bf16x8 af[4], bfr[4];
#pragma unroll
      for (int mi = 0; mi < 4; mi++) af[mi] = *(const bf16x8*)(As + (wm + mi * 16 + fr) * 64 + kk * 32 + fg * 8);
#pragma unroll
      for (int ni = 0; ni < 4; ni++) bfr[ni] = *(const bf16x8*)(Bs + (wn + ni * 16 + fr) * 64 + kk * 32 + fg * 8);
#pragma unroll
      for (int mi = 0; mi < 4; mi++)
#pragma unroll
        for (int ni = 0; ni < 4; ni++)
          acc[mi][ni] = __builtin_amdgcn_mfma_f32_16x16x32_bf16(af[mi], bfr[ni], acc[mi][ni], 0, 0, 0);
    }
    __syncthreads();
  }
}

// ---------------- QKV projection; fused z = 0:Q  1:K  2:V; XCD-chunked swizzle ----------------
__global__ __launch_bounds__(256) void qkv_gemm(const bf16* __restrict__ xb, const bf16* __restrict__ wb,
    const float* __restrict__ bq, const float* __restrict__ bk, const float* __restrict__ bv,
    bf16* __restrict__ qb, float* __restrict__ kout, float* __restrict__ vout, bf16* __restrict__ kbf) {
  __shared__ alignas(16) bf16 As[128 * 64];
  __shared__ alignas(16) bf16 Bs[128 * 64];
  f32x4 acc[4][4];
#pragma unroll
  for (int a = 0; a < 4; a++)
#pragma unroll
    for (int b = 0; b < 4; b++) acc[a][b] = (f32x4){0.f, 0.f, 0.f, 0.f};
  // T1: bijective XCD-chunked swizzle over flat grid (nwg=1536, 1536%8==0, cpx=192)
  const int flat = blockIdx.x + 16 * (blockIdx.y + 32 * blockIdx.z);
  const int swz = (flat & 7) * 192 + (flat >> 3);
  const int n0 = (swz & 15) * 128;
  const int m0 = ((swz >> 4) & 31) * 128;
  const int z = swz >> 9;
  gemm128_mainloop(xb, wb + (size_t)z * 4194304, m0, n0, As, Bs, acc);
  const int lane = threadIdx.x & 63, w = threadIdx.x >> 6;
  const int wm = (w >> 1) * 64, wn = (w & 1) * 64, fr = lane & 15, fg = lane >> 4;
  const float* bias = (z == 0) ? bq : (z == 1 ? bk : bv);
#pragma unroll
  for (int ni = 0; ni < 4; ni++) {
    int col = n0 + wn + ni * 16 + fr;
    float bi = bias[col];
#pragma unroll
    for (int mi = 0; mi < 4; mi++) {
#pragma unroll
      for (int r = 0; r < 4; r++) {
        int row = m0 + wm + mi * 16 + fg * 4 + r;
        float v = acc[mi][ni][r] + bi;
        if (z == 0) {
          // fold 1/sqrt(128) * log2(e) so attn can use v_exp_f32 (exp2) directly
          qb[(size_t)row * 2048 + col] = (bf16)(v * 0.12751744955867606f);
        } else {
          size_t co = (((size_t)(row >> 11) * 16 + (col >> 7)) * 4096 + 2048 + (row & 2047)) * 128 + (col & 127);
          if (z == 1) { kout[co] = v; kbf[co] = (bf16)v; }
          else        { vout[co] = v; }
        }
      }
    }
  }
}

// ---------------- V cache -> transposed bf16  [BH][128][4096] ----------------
__global__ __launch_bounds__(256) void build_vt(const float* __restrict__ vsrc, bf16* __restrict__ vtb) {
  __shared__ float tile[64][65];
  const int tid = threadIdx.x;
  const int bh = blockIdx.z;
  const int t0 = blockIdx.x * 64, d0 = blockIdx.y * 64;
  const float* src = vsrc + ((size_t)bh * LT + t0) * HD + d0;
#pragma unroll
  for (int i = 0; i < 4; i++) {
    int idx = i * 256 + tid;
    int rr = idx >> 4, c4 = (idx & 15) * 4;
    float4 v = *(const float4*)(src + rr * HD + c4);
    tile[rr][c4 + 0] = v.x; tile[rr][c4 + 1] = v.y; tile[rr][c4 + 2] = v.z; tile[rr][c4 + 3] = v.w;
  }
  __syncthreads();
  bf16* dst = vtb + (size_t)bh * HD * LT + (size_t)d0 * LT + t0;
#pragma unroll
  for (int i = 0; i < 4; i++) {
    int idx = i * 256 + tid;
    int dr = idx >> 4, c4 = (idx & 15) * 4;
    bf16x4 o = { (bf16)tile[c4 + 0][dr], (bf16)tile[c4 + 1][dr],
                 (bf16)tile[c4 + 2][dr], (bf16)tile[c4 + 3][dr] };
    *(bf16x4*)(dst + (size_t)dr * LT + c4) = o;
  }
}

// ---------------- flash attention: 4 waves x 32 q-rows, KVBLK=64 ----------------
// R7: hoist all 16 V-fragment ds_read_b128 ABOVE the P-pack + lgkmcnt(0)
//     (asm "memory" clobber was pinning them below the drain -> serial chain).
//     Structure otherwise = R6 (dbuf, 1 barrier/iter, setprio, bh-swizzle, DPP).
__global__ __launch_bounds__(256, 2) void attn(const bf16* __restrict__ qb, const bf16* __restrict__ kb,
                                               const bf16* __restrict__ vtb, bf16* __restrict__ ctxb) {
  __shared__ alignas(16) bf16 kbuf[2][64 * 128];    // [key][d], swizzled
  __shared__ alignas(16) bf16 vtbuf[2][128 * 64];   // [d][key], swizzled
  __shared__ alignas(16) bf16 pbuf[4][2][16 * 64];  // per-wave, per-set [q][key], swizzled
  const int tid = threadIdx.x, lane = tid & 63, w = tid >> 6;   // w in 0..3
  const int fr = lane & 15, fg = lane >> 4;
  // bh-grouped swizzle: linear id i -> XCD i&7 handles heads {4*(i&7) .. 4*(i&7)+3}
  const int i_ = blockIdx.x + 16 * blockIdx.y;   // 0..511
  const int j_ = i_ >> 3;
  const int bh = (i_ & 7) * 4 + (j_ & 3);
  const int q0 = (j_ >> 2) * 128;
  const int b = bh >> 4;
  // two 16-row q-sets per wave: rows q0 + w*32 + s*16 + {fr | fg*4+r}
  bf16x8 aq[2][4];
#pragma unroll
  for (int s = 0; s < 2; s++) {
    const bf16* qrow = qb + (size_t)(b * LQ + q0 + w * 32 + s * 16 + fr) * D_MODEL + (bh & 15) * HD;
#pragma unroll
    for (int c = 0; c < 4; c++) aq[s][c] = *(const bf16x8*)(qrow + c * 32 + fg * 8);
  }
  const bf16* Kb = kb + (size_t)bh * LT * HD;
  const bf16* Vt = vtb + (size_t)bh * HD * LT;
  float m_[2][4];
  f32x4 ctx[2][8], sum_[2];
#pragma unroll
  for (int s = 0; s < 2; s++) {
#pragma unroll
    for (int r = 0; r < 4; r++) m_[s][r] = -__builtin_inff();
#pragma unroll
    for (int d = 0; d < 8; d++) ctx[s][d] = (f32x4){0.f, 0.f, 0.f, 0.f};
    sum_[s] = (f32x4){0.f, 0.f, 0.f, 0.f};
  }
  bf16x8 vones;
#pragma unroll
  for (int j = 0; j < 8; j++) vones[j] = (bf16)1.0f;

  // staging: 256 threads, 4 rounds each for K (16 rows/round) and Vt (32 rows/round)
  // inverse-swizzled global source col, linear LDS dest (rule #21)
#define STAGE_KV(k0s, sel)                                                                   \
  do {                                                                                       \
    _Pragma("unroll")                                                                        \
    for (int j = 0; j < 4; j++) {                                                            \
      const int krow = j * 16 + w * 4 + (lane >> 4);                                         \
      const int kscol = ((lane & 15) ^ (krow & 7)) * 8;                                      \
      gload16(Kb + (size_t)((k0s) + krow) * HD + kscol, &kbuf[sel][(j * 16 + w * 4) * HD]);  \
      const int vrw = j * 32 + w * 8 + (lane >> 3);                                          \
      const int vscol = ((lane & 7) ^ (vrw & 7)) * 8;                                        \
      gload16(Vt + (size_t)vrw * LT + (k0s) + vscol, &vtbuf[sel][(j * 32 + w * 8) * 64]);    \
    }                                                                                        \
  } while (0)

  STAGE_KV(0, 0);
  int sel = 0;
  for (int k0 = 0; k0 < LT; k0 += 64) {
    __syncthreads();                       // buf[sel] staged; prev reads of buf[sel^1] done
    const int kn = (k0 + 64) & (LT - 1);   // wrap on last iter (harmless re-stage)
    STAGE_KV(kn, sel ^ 1);                 // overlaps with the whole compute below
    const bf16* kcur = &kbuf[sel][0];
    const bf16* vcur = &vtbuf[sel][0];
    // S = Q K^T for both q-sets; each kf read feeds 2 MFMAs
    f32x4 sS[2][4];
    __builtin_amdgcn_s_setprio(1);
#pragma unroll
    for (int n = 0; n < 4; n++) {
      sS[0][n] = (f32x4){0.f, 0.f, 0.f, 0.f};
      sS[1][n] = (f32x4){0.f, 0.f, 0.f, 0.f};
#pragma unroll
      for (int c = 0; c < 4; c++) {
        bf16x8 kf = *(const bf16x8*)(kcur + (n * 16 + fr) * HD + (((c * 4 + fg) ^ (fr & 7)) * 8));
        sS[0][n] = __builtin_amdgcn_mfma_f32_16x16x32_bf16(aq[0][c], kf, sS[0][n], 0, 0, 0);
        sS[1][n] = __builtin_amdgcn_mfma_f32_16x16x32_bf16(aq[1][c], kf, sS[1][n], 0, 0, 0);
      }
    }
    __builtin_amdgcn_s_setprio(0);
    // V fragments: issue ALL 16 ds_read_b128 now, before the P-pack and the
    // lgkmcnt(0) drain — they overlap the softmax VALU and share the wait.
    bf16x8 vf[16];
#pragma unroll
    for (int d = 0; d < 8; d++) {
      vf[d * 2 + 0] = *(const bf16x8*)(vcur + (d * 16 + fr) * 64 + ((fg ^ (fr & 7)) * 8));
      vf[d * 2 + 1] = *(const bf16x8*)(vcur + (d * 16 + fr) * 64 + (((4 + fg) ^ (fr & 7)) * 8));
    }
    // tile max per row (row q = fg*4+r within set), DPP rotate-reduce over 16-lane row
    float tmax[2][4];
    int ok = 1;
#pragma unroll
    for (int s = 0; s < 2; s++)
#pragma unroll
      for (int r = 0; r < 4; r++) {
        float t = fmaxf(fmaxf(sS[s][0][r], sS[s][1][r]), fmaxf(sS[s][2][r], sS[s][3][r]));
        t = rowmax16(t);
        tmax[s][r] = t;
        ok &= (t <= m_[s][r] + 8.f);
      }
    // defer-max: only rescale when some row's max grew past THR=8 (log2 units)
    if (!__all(ok)) {
#pragma unroll
      for (int s = 0; s < 2; s++)
#pragma unroll
        for (int r = 0; r < 4; r++) {
          float mn = fmaxf(m_[s][r], tmax[s][r]);
          float al = __builtin_amdgcn_exp2f(m_[s][r] - mn);
          m_[s][r] = mn;
#pragma unroll
          for (int d = 0; d < 8; d++) ctx[s][d][r] *= al;
          sum_[s][r] *= al;
        }
    }
    // P = exp2(S - m) -> per-wave LDS. Pair lanes via DPP quad_perm(1,0,3,2):
    // even-fr lanes write rows R+0,R+1 dwords; odd-fr rows R+2,R+3 -> 2 b32/ (s,n)
    {
      const int odd = fr & 1;
      const int ce = fr & ~1;
      const int rowA = fg * 4 + (odd ? 2 : 0);
      const int rowB = rowA + 1;
#pragma unroll
      for (int s = 0; s < 2; s++) {
        bf16* pw = &pbuf[w][s][0];
#pragma unroll
        for (int n = 0; n < 4; n++) {
          const int gr = n * 2 + (fr >> 3);
          uint bb[4], pp[4];
#pragma unroll
          for (int r = 0; r < 4; r++) {
            bf16 h = (bf16)__builtin_amdgcn_exp2f(sS[s][n][r] - m_[s][r]);
            unsigned short us;
            __builtin_memcpy(&us, &h, 2);
            bb[r] = us;
          }
#pragma unroll
          for (int r = 0; r < 4; r++)
            pp[r] = (uint)__builtin_amdgcn_update_dpp(0, (int)bb[r], 0xB1, 0xF, 0xF, true);
          uint d0 = odd ? (pp[2] | (bb[2] << 16)) : (bb[0] | (pp[0] << 16));
          uint d1 = odd ? (pp[3] | (bb[3] << 16)) : (bb[1] | (pp[1] << 16));
          *(uint*)&pw[rowA * 64 + ((gr ^ (rowA & 7)) * 8) + (ce & 7)] = d0;
          *(uint*)&pw[rowB * 64 + ((gr ^ (rowB & 7)) * 8) + (ce & 7)] = d1;
        }
      }
    }
    // wave-private buffer: in-wave ordering only (also drains the vf reads above)
    asm volatile("s_waitcnt lgkmcnt(0)" ::: "memory");
    bf16x8 pf[2][2];
#pragma unroll
    for (int s = 0; s < 2; s++) {
      const bf16* pw = &pbuf[w][s][0];
      pf[s][0] = *(const bf16x8*)(pw + fr * 64 + ((fg ^ (fr & 7)) * 8));
      pf[s][1] = *(const bf16x8*)(pw + fr * 64 + (((4 + fg) ^ (fr & 7)) * 8));
    }
    // PV: V fragments already in registers
    __builtin_amdgcn_s_setprio(1);
#pragma unroll
    for (int d = 0; d < 8; d++) {
      ctx[0][d] = __builtin_amdgcn_mfma_f32_16x16x32_bf16(pf[0][0], vf[d * 2 + 0], ctx[0][d], 0, 0, 0);
      ctx[1][d] = __builtin_amdgcn_mfma_f32_16x16x32_bf16(pf[1][0], vf[d * 2 + 0], ctx[1][d], 0, 0, 0);
      ctx[0][d] = __builtin_amdgcn_mfma_f32_16x16x32_bf16(pf[0][1], vf[d * 2 + 1], ctx[0][d], 0, 0, 0);
      ctx[1][d] = __builtin_amdgcn_mfma_f32_16x16x32_bf16(pf[1][1], vf[d * 2 + 1], ctx[1][d], 0, 0, 0);
    }
    // denominator via MFMA against all-ones B: every output col = row-sum of P
#pragma unroll
    for (int s = 0; s < 2; s++) {
      sum_[s] = __builtin_amdgcn_mfma_f32_16x16x32_bf16(pf[s][0], vones, sum_[s], 0, 0, 0);
      sum_[s] = __builtin_amdgcn_mfma_f32_16x16x32_bf16(pf[s][1], vones, sum_[s], 0, 0, 0);
    }
    __builtin_amdgcn_s_setprio(0);
    sel ^= 1;
  }
#undef STAGE_KV
#pragma unroll
  for (int s = 0; s < 2; s++) {
    float inv[4];
#pragma unroll
    for (int r = 0; r < 4; r++) inv[r] = 1.f / sum_[s][r];
    bf16* crow = ctxb + (size_t)(b * LQ + q0 + w * 32 + s * 16 + fg * 4) * D_MODEL + (bh & 15) * HD + fr;
#pragma unroll
    for (int r = 0; r < 4; r++)
#pragma unroll
      for (int d = 0; d < 8; d++)
        crow[(size_t)r * D_MODEL + d * 16] = (bf16)(ctx[s][d][r] * inv[r]);
  }
}

// ---------------- output projection; XCD-chunked swizzle ----------------
__global__ __launch_bounds__(256) void out_gemm(const bf16* __restrict__ cb, const bf16* __restrict__ wo,
                                                const float* __restrict__ bo, float* __restrict__ out) {
  __shared__ alignas(16) bf16 As[128 * 64];
  __shared__ alignas(16) bf16 Bs[128 * 64];
  f32x4 acc[4][4];
#pragma unroll
  for (int a = 0; a < 4; a++)
#pragma unroll
    for (int b = 0; b < 4; b++) acc[a][b] = (f32x4){0.f, 0.f, 0.f, 0.f};
  // T1: bijective XCD-chunked swizzle (nwg=512, cpx=64)
  const int flat = blockIdx.x + 16 * blockIdx.y;
  const int swz = (flat & 7) * 64 + (flat >> 3);
  const int n0 = (swz & 15) * 128;
  const int m0 = (swz >> 4) * 128;
  gemm128_mainloop(cb, wo, m0, n0, As, Bs, acc);
  const int lane = threadIdx.x & 63, w = threadIdx.x >> 6;
  const int wm = (w >> 1) * 64, wn = (w & 1) * 64, fr = lane & 15, fg = lane >> 4;
#pragma unroll
  for (int ni = 0; ni < 4; ni++) {
    int col = n0 + wn + ni * 16 + fr;
    float bi = bo[col];
#pragma unroll
    for (int mi = 0; mi < 4; mi++)
#pragma unroll
      for (int r = 0; r < 4; r++) {
        int row = m0 + wm + mi * 16 + fg * 4 + r;
        out[(size_t)row * 2048 + col] = acc[mi][ni][r] + bi;
      }
  }
}

extern "C" void kernel_launch(void* const* d_in, const int* in_sizes, int n_in,
                              void* d_out, int out_size, void* d_ws, size_t ws_size,
                              hipStream_t stream) {
  const float* x  = (const float*)d_in[0];
  const float* pk = (const float*)d_in[1];
  const float* pv = (const float*)d_in[2];
  const float* Wq = (const float*)d_in[3];
  const float* bq = (const float*)d_in[4];
  const float* Wk = (const float*)d_in[5];
  const float* bk = (const float*)d_in[6];
  const float* Wv = (const float*)d_in[7];
  const float* bv = (const float*)d_in[8];
  const float* Wo = (const float*)d_in[9];
  const float* bo = (const float*)d_in[10];

  float* out  = (float*)d_out;
  float* kout = out + 8388608;   // B*L*D
  float* vout = out + 25165824;

  char* p = (char*)d_ws;
  bf16* xb  = (bf16*)p;                   // 16 MiB, reused as ctxb after QKV gemm
  bf16* wb  = (bf16*)(p + 16777216);      // 32 MiB: Wq,Wk,Wv,Wo bf16
  bf16* qb  = (bf16*)(p + 50331648);      // 16 MiB (pre-scaled Q)
  bf16* kbf = (bf16*)(p + 67108864);      // 32 MiB K cache bf16 [BH][4096][128]
  bf16* vtb = (bf16*)(p + 100663296);     // 32 MiB V^T cache bf16 [BH][128][4096]
  bf16* ctxb = xb;

  conv_bf16<<<8192, 256, 0, stream>>>(x, xb, 8388608);
  conv_w4<<<dim3(4096, 4), 256, 0, stream>>>(Wq, Wk, Wv, Wo, wb);
  copy_past<<<8192, 256, 0, stream>>>(pk, kout, kbf);
  copy_past<<<8192, 256, 0, stream>>>(pv, vout, nullptr);

  qkv_gemm<<<dim3(16, 32, 3), 256, 0, stream>>>(xb, wb, bq, bk, bv, qb, kout, vout, kbf);
  build_vt<<<dim3(64, 2, 32), 256, 0, stream>>>(vout, vtb);
  attn<<<dim3(16, 32), 256, 0, stream>>>(qb, kbf, vtb, ctxb);
  out_gemm<<<dim3(16, 32), 256, 0, stream>>>(ctxb, wb + 12582912, bo, out);
}

// Round 9
// 451.825 us; speedup vs baseline: 1.7662x; 1.1017x over previous
//
#include <hip/hip_runtime.h>
#include <cstdint>
#include <cstddef>

typedef __bf16 bf16;
typedef __bf16 bf16x8 __attribute__((ext_vector_type(8)));
typedef __bf16 bf16x4 __attribute__((ext_vector_type(4)));
typedef float f32x4 __attribute__((ext_vector_type(4)));
typedef unsigned int uint;

#define D_MODEL 2048
#define NH 16
#define HD 128
#define LQ 2048
#define LT 4096

__device__ __forceinline__ void gload16(const void* g, void* l) {
  __builtin_amdgcn_global_load_lds((const __attribute__((address_space(1))) void*)g,
                                   (__attribute__((address_space(3))) void*)l, 16, 0, 0);
}

// ---------------- elementwise fp32 -> bf16 ----------------
__global__ __launch_bounds__(256) void conv_bf16(const float* __restrict__ s, bf16* __restrict__ d, int n) {
  int i = (blockIdx.x * 256 + threadIdx.x) * 4;
  if (i >= n) return;
  float4 v = *(const float4*)(s + i);
  bf16x4 o = { (bf16)v.x, (bf16)v.y, (bf16)v.z, (bf16)v.w };
  *(bf16x4*)(d + i) = o;
}

// fused 4-weight convert: grid (4096, 4); each y-slice is one 2048x2048 matrix
__global__ __launch_bounds__(256) void conv_w4(const float* __restrict__ a, const float* __restrict__ b,
                                               const float* __restrict__ c, const float* __restrict__ d,
                                               bf16* __restrict__ o) {
  const int z = blockIdx.y;
  const float* s = (z == 0) ? a : (z == 1) ? b : (z == 2) ? c : d;
  int i = (blockIdx.x * 256 + threadIdx.x) * 4;
  float4 v = *(const float4*)(s + i);
  bf16x4 ov = { (bf16)v.x, (bf16)v.y, (bf16)v.z, (bf16)v.w };
  *(bf16x4*)(o + (size_t)z * 4194304 + i) = ov;
}

// ---------------- copy past K/V into cache (fp32 out, optional bf16) ----------------
// src layout [BH][2048][128]; dst layout [BH][4096][128] rows 0..2047
__global__ __launch_bounds__(256) void copy_past(const float* __restrict__ src, float* __restrict__ dstf,
                                                 bf16* __restrict__ dstb) {
  int i = (blockIdx.x * 256 + threadIdx.x) * 4;
  int bh = i >> 18;          // / (2048*128)
  int rem = i & 262143;
  size_t o = ((size_t)bh << 19) + rem;   // * (4096*128)
  float4 v = *(const float4*)(src + i);
  *(float4*)(dstf + o) = v;
  if (dstb) {
    bf16x4 ob = { (bf16)v.x, (bf16)v.y, (bf16)v.z, (bf16)v.w };
    *(bf16x4*)(dstb + o) = ob;
  }
}

// ---------------- shared 128x128 bf16 GEMM mainloop (C = A * B^T), K = 2048 ----------------
__device__ __forceinline__ void gemm128_mainloop(const bf16* __restrict__ A, const bf16* __restrict__ B,
                                                 int m0, int n0, bf16* As, bf16* Bs, f32x4 (&acc)[4][4]) {
  const int tid = threadIdx.x, lane = tid & 63, w = tid >> 6;
  const int srow = w * 8 + (lane >> 3), scol = (lane & 7) * 8;
  const int wm = (w >> 1) * 64, wn = (w & 1) * 64, fr = lane & 15, fg = lane >> 4;
  for (int k0 = 0; k0 < 2048; k0 += 64) {
#pragma unroll
    for (int i = 0; i < 4; i++) {
      gload16(A + (size_t)(m0 + i * 32 + srow) * 2048 + k0 + scol, As + (i * 32 + w * 8) * 64);
      gload16(B + (size_t)(n0 + i * 32 + srow) * 2048 + k0 + scol, Bs + (i * 32 + w * 8) * 64);
    }
    __syncthreads();
#pragma unroll
    for (int kk = 0; kk < 2; kk++) {
      bf16x8 af[4], bfr[4];
#pragma unroll
      for (int mi = 0; mi < 4; mi++) af[mi] = *(const bf16x8*)(As + (wm + mi * 16 + fr) * 64 + kk * 32 + fg * 8);
#pragma unroll
      for (int ni = 0; ni < 4; ni++) bfr[ni] = *(const bf16x8*)(Bs + (wn + ni * 16 + fr) * 64 + kk * 32 + fg * 8);
#pragma unroll
      for (int mi = 0; mi < 4; mi++)
#pragma unroll
        for (int ni = 0; ni < 4; ni++)
          acc[mi][ni] = __builtin_amdgcn_mfma_f32_16x16x32_bf16(af[mi], bfr[ni], acc[mi][ni], 0, 0, 0);
    }
    __syncthreads();
  }
}

// ---------------- QKV projection; fused z = 0:Q  1:K  2:V; XCD-chunked swizzle ----------------
__global__ __launch_bounds__(256) void qkv_gemm(const bf16* __restrict__ xb, const bf16* __restrict__ wb,
    const float* __restrict__ bq, const float* __restrict__ bk, const float* __restrict__ bv,
    bf16* __restrict__ qb, float* __restrict__ kout, float* __restrict__ vout, bf16* __restrict__ kbf) {
  __shared__ alignas(16) bf16 As[128 * 64];
  __shared__ alignas(16) bf16 Bs[128 * 64];
  f32x4 acc[4][4];
#pragma unroll
  for (int a = 0; a < 4; a++)
#pragma unroll
    for (int b = 0; b < 4; b++) acc[a][b] = (f32x4){0.f, 0.f, 0.f, 0.f};
  // T1: bijective XCD-chunked swizzle over flat grid (nwg=1536, 1536%8==0, cpx=192)
  const int flat = blockIdx.x + 16 * (blockIdx.y + 32 * blockIdx.z);
  const int swz = (flat & 7) * 192 + (flat >> 3);
  const int n0 = (swz & 15) * 128;
  const int m0 = ((swz >> 4) & 31) * 128;
  const int z = swz >> 9;
  gemm128_mainloop(xb, wb + (size_t)z * 4194304, m0, n0, As, Bs, acc);
  const int lane = threadIdx.x & 63, w = threadIdx.x >> 6;
  const int wm = (w >> 1) * 64, wn = (w & 1) * 64, fr = lane & 15, fg = lane >> 4;
  const float* bias = (z == 0) ? bq : (z == 1 ? bk : bv);
#pragma unroll
  for (int ni = 0; ni < 4; ni++) {
    int col = n0 + wn + ni * 16 + fr;
    float bi = bias[col];
#pragma unroll
    for (int mi = 0; mi < 4; mi++) {
#pragma unroll
      for (int r = 0; r < 4; r++) {
        int row = m0 + wm + mi * 16 + fg * 4 + r;
        float v = acc[mi][ni][r] + bi;
        if (z == 0) {
          // fold 1/sqrt(128) * log2(e) so attn can use v_exp_f32 (exp2) directly
          qb[(size_t)row * 2048 + col] = (bf16)(v * 0.12751744955867606f);
        } else {
          size_t co = (((size_t)(row >> 11) * 16 + (col >> 7)) * 4096 + 2048 + (row & 2047)) * 128 + (col & 127);
          if (z == 1) { kout[co] = v; kbf[co] = (bf16)v; }
          else        { vout[co] = v; }
        }
      }
    }
  }
}

// ---------------- V cache -> transposed bf16  [BH][128][4096] ----------------
__global__ __launch_bounds__(256) void build_vt(const float* __restrict__ vsrc, bf16* __restrict__ vtb) {
  __shared__ float tile[64][65];
  const int tid = threadIdx.x;
  const int bh = blockIdx.z;
  const int t0 = blockIdx.x * 64, d0 = blockIdx.y * 64;
  const float* src = vsrc + ((size_t)bh * LT + t0) * HD + d0;
#pragma unroll
  for (int i = 0; i < 4; i++) {
    int idx = i * 256 + tid;
    int rr = idx >> 4, c4 = (idx & 15) * 4;
    float4 v = *(const float4*)(src + rr * HD + c4);
    tile[rr][c4 + 0] = v.x; tile[rr][c4 + 1] = v.y; tile[rr][c4 + 2] = v.z; tile[rr][c4 + 3] = v.w;
  }
  __syncthreads();
  bf16* dst = vtb + (size_t)bh * HD * LT + (size_t)d0 * LT + t0;
#pragma unroll
  for (int i = 0; i < 4; i++) {
    int idx = i * 256 + tid;
    int dr = idx >> 4, c4 = (idx & 15) * 4;
    bf16x4 o = { (bf16)tile[c4 + 0][dr], (bf16)tile[c4 + 1][dr],
                 (bf16)tile[c4 + 2][dr], (bf16)tile[c4 + 3][dr] };
    *(bf16x4*)(dst + (size_t)dr * LT + c4) = o;
  }
}

// ---------------- flash attention: 4 waves x 32 q-rows, KVBLK=64 ----------------
// R8: swapped QK^T (mfma(K,Q)) puts S in col=q layout -> softmax lane-local;
//     P reaches PV A-fragment layout via packed-dword permlane32/16_swap pairs
//     (key = 32c + 8*fg + 2*pos + {0,1} mapping, derived from verified layouts).
//     Eliminates the P LDS round-trip (pack->ds_write->lgkmcnt(0)->ds_read) and
//     pbuf (LDS 80->64 KiB). Denominator stays on MFMA-ones (ctx row layout).
__global__ __launch_bounds__(256, 2) void attn(const bf16* __restrict__ qb, const bf16* __restrict__ kb,
                                               const bf16* __restrict__ vtb, bf16* __restrict__ ctxb) {
  __shared__ alignas(16) bf16 kbuf[2][64 * 128];    // [key][d], swizzled
  __shared__ alignas(16) bf16 vtbuf[2][128 * 64];   // [d][key], swizzled
  const int tid = threadIdx.x, lane = tid & 63, w = tid >> 6;   // w in 0..3
  const int fr = lane & 15, fg = lane >> 4;
  // bh-grouped swizzle: linear id i -> XCD i&7 handles heads {4*(i&7) .. 4*(i&7)+3}
  const int i_ = blockIdx.x + 16 * blockIdx.y;   // 0..511
  const int j_ = i_ >> 3;
  const int bh = (i_ & 7) * 4 + (j_ & 3);
  const int q0 = (j_ >> 2) * 128;
  const int b = bh >> 4;
  // two 16-row q-sets per wave: q = q0 + w*32 + s*16 + fr (col index after swap)
  bf16x8 aq[2][4];
#pragma unroll
  for (int s = 0; s < 2; s++) {
    const bf16* qrow = qb + (size_t)(b * LQ + q0 + w * 32 + s * 16 + fr) * D_MODEL + (bh & 15) * HD;
#pragma unroll
    for (int c = 0; c < 4; c++) aq[s][c] = *(const bf16x8*)(qrow + c * 32 + fg * 8);
  }
  const bf16* Kb = kb + (size_t)bh * LT * HD;
  const bf16* Vt = vtb + (size_t)bh * HD * LT;
  float m_[2];                       // running max for lane's q (per set)
  f32x4 ctx[2][8], sum_[2];          // ctx/sum in ROW layout (q = fg*4+r)
#pragma unroll
  for (int s = 0; s < 2; s++) {
    m_[s] = -__builtin_inff();
#pragma unroll
    for (int d = 0; d < 8; d++) ctx[s][d] = (f32x4){0.f, 0.f, 0.f, 0.f};
    sum_[s] = (f32x4){0.f, 0.f, 0.f, 0.f};
  }
  bf16x8 vones;
#pragma unroll
  for (int j = 0; j < 8; j++) vones[j] = (bf16)1.0f;

  // staging: 256 threads, 4 rounds each for K (16 rows/round) and Vt (32 rows/round)
  // inverse-swizzled global source col, linear LDS dest (rule #21)
#define STAGE_KV(k0s, sel)                                                                   \
  do {                                                                                       \
    _Pragma("unroll")                                                                        \
    for (int j = 0; j < 4; j++) {                                                            \
      const int krow = j * 16 + w * 4 + (lane >> 4);                                         \
      const int kscol = ((lane & 15) ^ (krow & 7)) * 8;                                      \
      gload16(Kb + (size_t)((k0s) + krow) * HD + kscol, &kbuf[sel][(j * 16 + w * 4) * HD]);  \
      const int vrw = j * 32 + w * 8 + (lane >> 3);                                          \
      const int vscol = ((lane & 7) ^ (vrw & 7)) * 8;                                        \
      gload16(Vt + (size_t)vrw * LT + (k0s) + vscol, &vtbuf[sel][(j * 32 + w * 8) * 64]);    \
    }                                                                                        \
  } while (0)

  STAGE_KV(0, 0);
  int sel = 0;
  for (int k0 = 0; k0 < LT; k0 += 64) {
    __syncthreads();                       // buf[sel] staged; prev reads of buf[sel^1] done
    const int kn = (k0 + 64) & (LT - 1);   // wrap on last iter (harmless re-stage)
    STAGE_KV(kn, sel ^ 1);                 // overlaps with the whole compute below
    const bf16* kcur = &kbuf[sel][0];
    const bf16* vcur = &vtbuf[sel][0];
    // S^T = K Q^T: sS[s][n][r] = S[key = n*16 + fg*4 + r][q = set s, col fr]
    f32x4 sS[2][4];
    __builtin_amdgcn_s_setprio(1);
#pragma unroll
    for (int n = 0; n < 4; n++) {
      sS[0][n] = (f32x4){0.f, 0.f, 0.f, 0.f};
      sS[1][n] = (f32x4){0.f, 0.f, 0.f, 0.f};
#pragma unroll
      for (int c = 0; c < 4; c++) {
        bf16x8 kf = *(const bf16x8*)(kcur + (n * 16 + fr) * HD + (((c * 4 + fg) ^ (fr & 7)) * 8));
        sS[0][n] = __builtin_amdgcn_mfma_f32_16x16x32_bf16(kf, aq[0][c], sS[0][n], 0, 0, 0);
        sS[1][n] = __builtin_amdgcn_mfma_f32_16x16x32_bf16(kf, aq[1][c], sS[1][n], 0, 0, 0);
      }
    }
    __builtin_amdgcn_s_setprio(0);
    // tile max per q: lane-local over 16 values + cross-fg butterfly (permlane swaps)
    float tm[2];
    int ok = 1;
#pragma unroll
    for (int s = 0; s < 2; s++) {
      float t = sS[s][0][0];
#pragma unroll
      for (int n = 0; n < 4; n++)
#pragma unroll
        for (int r = 0; r < 4; r++) if (n | r) t = fmaxf(t, sS[s][n][r]);
      float c1 = t;
      asm("v_permlane32_swap_b32 %0, %1" : "+v"(t), "+v"(c1));
      t = fmaxf(t, c1);
      float c2 = t;
      asm("v_permlane16_swap_b32 %0, %1" : "+v"(t), "+v"(c2));
      t = fmaxf(t, c2);
      tm[s] = t;
      ok &= (t <= m_[s] + 8.f);
    }
    // defer-max: rescale only when some q's max grew past THR=8 (log2 units)
    if (!__all(ok)) {
#pragma unroll
      for (int s = 0; s < 2; s++) {
        float mn = fmaxf(m_[s], tm[s]);
        float al = __builtin_amdgcn_exp2f(m_[s] - mn);
        m_[s] = mn;
#pragma unroll
        for (int r = 0; r < 4; r++) {
          float a4 = __shfl(al, fg * 4 + r);   // lane q=fr -> row q=fg*4+r
#pragma unroll
          for (int d = 0; d < 8; d++) ctx[s][d][r] *= a4;
          sum_[s][r] *= a4;
        }
      }
    }
    // P = exp2(S - m): pack bf16 pairs along r, permlane-redistribute to A-frags
    bf16x8 pf[2][2];
#pragma unroll
    for (int s = 0; s < 2; s++) {
      uint Dd[4][2];
#pragma unroll
      for (int n = 0; n < 4; n++) {
        uint hb[4];
#pragma unroll
        for (int r = 0; r < 4; r++) {
          bf16 h = (bf16)__builtin_amdgcn_exp2f(sS[s][n][r] - m_[s]);
          unsigned short us;
          __builtin_memcpy(&us, &h, 2);
          hb[r] = us;
        }
        Dd[n][0] = hb[0] | (hb[1] << 16);
        Dd[n][1] = hb[2] | (hb[3] << 16);
      }
#pragma unroll
      for (int c = 0; c < 2; c++) {
        uint T[4];
#pragma unroll
        for (int p = 0; p < 2; p++) {
          uint a = Dd[2 * c][p], b2 = Dd[2 * c + 1][p];
          asm("v_permlane32_swap_b32 %0, %1" : "+v"(a), "+v"(b2));
          asm("v_permlane16_swap_b32 %0, %1" : "+v"(a), "+v"(b2));
          T[p] = a; T[2 + p] = b2;
        }
        union { uint u[4]; bf16x8 v; } cv;
        cv.u[0] = T[0]; cv.u[1] = T[1]; cv.u[2] = T[2]; cv.u[3] = T[3];
        pf[s][c] = cv.v;
      }
    }
    // PV: ctx[q-row][d] += P * V (V fragments read inline from LDS)
    __builtin_amdgcn_s_setprio(1);
#pragma unroll
    for (int d = 0; d < 8; d++) {
      bf16x8 v0 = *(const bf16x8*)(vcur + (d * 16 + fr) * 64 + ((fg ^ (fr & 7)) * 8));
      ctx[0][d] = __builtin_amdgcn_mfma_f32_16x16x32_bf16(pf[0][0], v0, ctx[0][d], 0, 0, 0);
      ctx[1][d] = __builtin_amdgcn_mfma_f32_16x16x32_bf16(pf[1][0], v0, ctx[1][d], 0, 0, 0);
      bf16x8 v1 = *(const bf16x8*)(vcur + (d * 16 + fr) * 64 + (((4 + fg) ^ (fr & 7)) * 8));
      ctx[0][d] = __builtin_amdgcn_mfma_f32_16x16x32_bf16(pf[0][1], v1, ctx[0][d], 0, 0, 0);
      ctx[1][d] = __builtin_amdgcn_mfma_f32_16x16x32_bf16(pf[1][1], v1, ctx[1][d], 0, 0, 0);
    }
    // denominator via MFMA against all-ones B (rows = q -> matches ctx layout)
#pragma unroll
    for (int s = 0; s < 2; s++) {
      sum_[s] = __builtin_amdgcn_mfma_f32_16x16x32_bf16(pf[s][0], vones, sum_[s], 0, 0, 0);
      sum_[s] = __builtin_amdgcn_mfma_f32_16x16x32_bf16(pf[s][1], vones, sum_[s], 0, 0, 0);
    }
    __builtin_amdgcn_s_setprio(0);
    sel ^= 1;
  }
#undef STAGE_KV
#pragma unroll
  for (int s = 0; s < 2; s++) {
    float inv[4];
#pragma unroll
    for (int r = 0; r < 4; r++) inv[r] = 1.f / sum_[s][r];
    bf16* crow = ctxb + (size_t)(b * LQ + q0 + w * 32 + s * 16 + fg * 4) * D_MODEL + (bh & 15) * HD + fr;
#pragma unroll
    for (int r = 0; r < 4; r++)
#pragma unroll
      for (int d = 0; d < 8; d++)
        crow[(size_t)r * D_MODEL + d * 16] = (bf16)(ctx[s][d][r] * inv[r]);
  }
}

// ---------------- output projection; XCD-chunked swizzle ----------------
__global__ __launch_bounds__(256) void out_gemm(const bf16* __restrict__ cb, const bf16* __restrict__ wo,
                                                const float* __restrict__ bo, float* __restrict__ out) {
  __shared__ alignas(16) bf16 As[128 * 64];
  __shared__ alignas(16) bf16 Bs[128 * 64];
  f32x4 acc[4][4];
#pragma unroll
  for (int a = 0; a < 4; a++)
#pragma unroll
    for (int b = 0; b < 4; b++) acc[a][b] = (f32x4){0.f, 0.f, 0.f, 0.f};
  // T1: bijective XCD-chunked swizzle (nwg=512, cpx=64)
  const int flat = blockIdx.x + 16 * blockIdx.y;
  const int swz = (flat & 7) * 64 + (flat >> 3);
  const int n0 = (swz & 15) * 128;
  const int m0 = (swz >> 4) * 128;
  gemm128_mainloop(cb, wo, m0, n0, As, Bs, acc);
  const int lane = threadIdx.x & 63, w = threadIdx.x >> 6;
  const int wm = (w >> 1) * 64, wn = (w & 1) * 64, fr = lane & 15, fg = lane >> 4;
#pragma unroll
  for (int ni = 0; ni < 4; ni++) {
    int col = n0 + wn + ni * 16 + fr;
    float bi = bo[col];
#pragma unroll
    for (int mi = 0; mi < 4; mi++)
#pragma unroll
      for (int r = 0; r < 4; r++) {
        int row = m0 + wm + mi * 16 + fg * 4 + r;
        out[(size_t)row * 2048 + col] = acc[mi][ni][r] + bi;
      }
  }
}

extern "C" void kernel_launch(void* const* d_in, const int* in_sizes, int n_in,
                              void* d_out, int out_size, void* d_ws, size_t ws_size,
                              hipStream_t stream) {
  const float* x  = (const float*)d_in[0];
  const float* pk = (const float*)d_in[1];
  const float* pv = (const float*)d_in[2];
  const float* Wq = (const float*)d_in[3];
  const float* bq = (const float*)d_in[4];
  const float* Wk = (const float*)d_in[5];
  const float* bk = (const float*)d_in[6];
  const float* Wv = (const float*)d_in[7];
  const float* bv = (const float*)d_in[8];
  const float* Wo = (const float*)d_in[9];
  const float* bo = (const float*)d_in[10];

  float* out  = (float*)d_out;
  float* kout = out + 8388608;   // B*L*D
  float* vout = out + 25165824;

  char* p = (char*)d_ws;
  bf16* xb  = (bf16*)p;                   // 16 MiB, reused as ctxb after QKV gemm
  bf16* wb  = (bf16*)(p + 16777216);      // 32 MiB: Wq,Wk,Wv,Wo bf16
  bf16* qb  = (bf16*)(p + 50331648);      // 16 MiB (pre-scaled Q)
  bf16* kbf = (bf16*)(p + 67108864);      // 32 MiB K cache bf16 [BH][4096][128]
  bf16* vtb = (bf16*)(p + 100663296);     // 32 MiB V^T cache bf16 [BH][128][4096]
  bf16* ctxb = xb;

  conv_bf16<<<8192, 256, 0, stream>>>(x, xb, 8388608);
  conv_w4<<<dim3(4096, 4), 256, 0, stream>>>(Wq, Wk, Wv, Wo, wb);
  copy_past<<<8192, 256, 0, stream>>>(pk, kout, kbf);
  copy_past<<<8192, 256, 0, stream>>>(pv, vout, nullptr);

  qkv_gemm<<<dim3(16, 32, 3), 256, 0, stream>>>(xb, wb, bq, bk, bv, qb, kout, vout, kbf);
  build_vt<<<dim3(64, 2, 32), 256, 0, stream>>>(vout, vtb);
  attn<<<dim3(16, 32), 256, 0, stream>>>(qb, kbf, vtb, ctxb);
  out_gemm<<<dim3(16, 32), 256, 0, stream>>>(ctxb, wb + 12582912, bo, out);
}